// Round 1
// baseline (3315.775 us; speedup 1.0000x reference)
//
#include <hip/hip_runtime.h>
#include <math.h>

// Problem constants
#define NN 256
#define KK 512
#define JJ 6
#define BB 8
#define MPTS 100000
// K/(2*pi)
#define KF_SCALE 81.48733086305615f

// ---------- device helpers ----------

// Abramowitz & Stegun 9.8.1 / 9.8.2 modified Bessel I0, float
__device__ __forceinline__ float i0f_dev(float x) {
    float ax = fabsf(x);
    if (ax < 3.75f) {
        float t = x / 3.75f; t *= t;
        return 1.0f + t*(3.5156229f + t*(3.0899424f + t*(1.2067492f +
               t*(0.2659732f + t*(0.0360768f + t*0.0045813f)))));
    } else {
        float t = 3.75f / ax;
        return (expf(ax) * rsqrtf(ax)) *
               (0.39894228f + t*(0.01328592f + t*(0.00225319f + t*(-0.00157565f +
                t*(0.00916281f + t*(-0.02057706f + t*(0.02635537f +
                t*(-0.01647633f + t*0.00392377f))))))));
    }
}

// Kaiser-Bessel kernel value at distance t
__device__ __forceinline__ float kbf(float t, float beta, float inv_i0b) {
    float u = t * (1.0f / 3.0f);       // 2*t/J, J=6
    float q = fmaxf(1.0f - u * u, 0.0f);
    return i0f_dev(beta * sqrtf(q)) * inv_i0b;
}

// ---------- kernels ----------

// One thread per (b, m): scatter 36 complex contributions into grid[b][][].
__global__ __launch_bounds__(256) void grid_scatter(
    const float* __restrict__ y_real, const float* __restrict__ y_imag,
    const float* __restrict__ weights, const float* __restrict__ uv,
    float* __restrict__ grid, float beta, float inv_i0b)
{
    int t = blockIdx.x * 256 + threadIdx.x;
    if (t >= BB * MPTS) return;
    int b = t / MPTS;
    int m = t - b * MPTS;

    float kf0 = uv[2 * m]     * KF_SCALE;
    float kf1 = uv[2 * m + 1] * KF_SCALE;
    float f0 = floorf(kf0), f1 = floorf(kf1);
    int ib0 = (int)f0, ib1 = (int)f1;

    float w0[JJ], w1[JJ];
    int id0[JJ], id1[JJ];
#pragma unroll
    for (int j = 0; j < JJ; ++j) {
        float off = (float)(j - 2);                // offs = -2..3
        w0[j] = kbf(f0 + off - kf0, beta, inv_i0b);
        w1[j] = kbf(f1 + off - kf1, beta, inv_i0b);
        id0[j] = (ib0 + j - 2) & (KK - 1);         // floored mod for pow2
        id1[j] = (ib1 + j - 2) & (KK - 1);
    }

    float wm = weights[m];
    float ar = y_real[t] * wm;
    float ai = y_imag[t] * wm;

    float* gb = grid + (size_t)b * KK * KK * 2;
#pragma unroll
    for (int j1 = 0; j1 < JJ; ++j1) {
        float* row = gb + id0[j1] * (KK * 2);
        float wj = w0[j1];
#pragma unroll
        for (int j2 = 0; j2 < JJ; ++j2) {
            float ww = wj * w1[j2];
            float* cell = row + id1[j2] * 2;
            unsafeAtomicAdd(cell,     ar * ww);
            unsafeAtomicAdd(cell + 1, ai * ww);
        }
    }
}

// Stage 1: G[b][r][k2] = sum_k1 grid[b][k1][k2] * e^{+2pi i k1 x1 / 512},
// x1 = (384 + r) & 511, r in [0,256). Block handles one b and 8 r-rows;
// 256 threads each own k2 = {t, t+256}.
__global__ __launch_bounds__(256) void dft_rows(
    const float* __restrict__ grid, float* __restrict__ G)
{
    __shared__ float twc[KK], tws[KK];
    int b = blockIdx.x >> 5;
    int r0 = (blockIdx.x & 31) * 8;
    int t = threadIdx.x;

    for (int p = t; p < KK; p += 256) {
        float ang = (float)(2.0 * M_PI / (double)KK) * (float)p;
        float s, c; sincosf(ang, &s, &c);
        twc[p] = c; tws[p] = s;
    }
    __syncthreads();

    int x1[8], ph[8];
    float accR0[8], accI0[8], accR1[8], accI1[8];
#pragma unroll
    for (int rr = 0; rr < 8; ++rr) {
        x1[rr] = (384 + r0 + rr) & (KK - 1);
        ph[rr] = 0;
        accR0[rr] = accI0[rr] = accR1[rr] = accI1[rr] = 0.0f;
    }

    const float2* g2 = (const float2*)(grid + (size_t)b * KK * KK * 2);
    for (int k1 = 0; k1 < KK; ++k1) {
        float2 ga = g2[k1 * KK + t];
        float2 gb = g2[k1 * KK + t + 256];
#pragma unroll
        for (int rr = 0; rr < 8; ++rr) {
            int p = ph[rr];
            float c = twc[p], s = tws[p];
            accR0[rr] += ga.x * c - ga.y * s;
            accI0[rr] += ga.x * s + ga.y * c;
            accR1[rr] += gb.x * c - gb.y * s;
            accI1[rr] += gb.x * s + gb.y * c;
            ph[rr] = (p + x1[rr]) & (KK - 1);
        }
    }

    float2* Gout = (float2*)G;
#pragma unroll
    for (int rr = 0; rr < 8; ++rr) {
        size_t base = ((size_t)b * NN + (r0 + rr)) * KK;
        Gout[base + t]       = make_float2(accR0[rr], accI0[rr]);
        Gout[base + t + 256] = make_float2(accR1[rr], accI1[rr]);
    }
}

// Stage 2: img[b][r][s] = Re( sum_k2 G[b][r][k2] e^{+2pi i k2 x2/512} ) / K^2 / apod
__global__ __launch_bounds__(256) void dft_cols(
    const float* __restrict__ G, float* __restrict__ img, float beta2)
{
    __shared__ float twc[KK], tws[KK], gr[KK], gi[KK];
    int b = blockIdx.x >> 8;
    int r = blockIdx.x & 255;
    int t = threadIdx.x;

    const float2* Grow = (const float2*)G + ((size_t)b * NN + r) * KK;
    for (int p = t; p < KK; p += 256) {
        float ang = (float)(2.0 * M_PI / (double)KK) * (float)p;
        float s, c; sincosf(ang, &s, &c);
        twc[p] = c; tws[p] = s;
        float2 g = Grow[p];
        gr[p] = g.x; gi[p] = g.y;
    }
    __syncthreads();

    int x2 = (384 + t) & (KK - 1);
    float acc = 0.0f;
    int p = 0;
    for (int k2 = 0; k2 < KK; ++k2) {
        float c = twc[p], s = tws[p];
        acc += gr[k2] * c - gi[k2] * s;
        p = (p + x2) & (KK - 1);
    }

    // apodization: d(n) = sinh(sqrt(arg))/sqrt(arg), arg = beta^2 - (pi*J*n/K)^2
    const float XF = (float)(M_PI * (double)JJ / (double)KK);
    float nr = (float)(r - 128), ns = (float)(t - 128);
    float xfr = XF * nr, xfs = XF * ns;
    float ar_ = beta2 - xfr * xfr;
    float as_ = beta2 - xfs * xfs;
    float sr = sqrtf(ar_), ss = sqrtf(as_);
    float dr = sinhf(sr) / sr;
    float ds = sinhf(ss) / ss;

    float val = acc * (1.0f / ((float)KK * (float)KK)) / (dr * ds);
    img[((size_t)b * NN + r) * NN + t] = val;
}

// Per-batch min/max: one block per batch.
__global__ __launch_bounds__(1024) void minmax_k(
    const float* __restrict__ img, float* __restrict__ mm)
{
    int b = blockIdx.x;
    const float* p = img + (size_t)b * NN * NN;
    float lmin = 1e30f, lmax = -1e30f;
    for (int i = threadIdx.x; i < NN * NN; i += 1024) {
        float v = p[i];
        lmin = fminf(lmin, v);
        lmax = fmaxf(lmax, v);
    }
#pragma unroll
    for (int off = 32; off >= 1; off >>= 1) {
        lmin = fminf(lmin, __shfl_down(lmin, off));
        lmax = fmaxf(lmax, __shfl_down(lmax, off));
    }
    __shared__ float smin[16], smax[16];
    int wave = threadIdx.x >> 6;
    if ((threadIdx.x & 63) == 0) { smin[wave] = lmin; smax[wave] = lmax; }
    __syncthreads();
    if (threadIdx.x == 0) {
        float mn = smin[0], mx = smax[0];
        for (int w = 1; w < 16; ++w) {
            mn = fminf(mn, smin[w]);
            mx = fmaxf(mx, smax[w]);
        }
        mm[2 * b] = mn;
        mm[2 * b + 1] = mx;
    }
}

__global__ __launch_bounds__(256) void norm_k(
    const float* __restrict__ img, const float* __restrict__ mm,
    float* __restrict__ out)
{
    int i = blockIdx.x * 256 + threadIdx.x;
    if (i >= BB * NN * NN) return;
    int b = i >> 16;
    float mn = mm[2 * b], mx = mm[2 * b + 1];
    out[i] = (img[i] - mn) / (mx - mn);
}

// ---------- host ----------

static double i0_host(double x) {
    double sum = 1.0, term = 1.0;
    double q = x * x * 0.25;
    for (int k = 1; k < 80; ++k) {
        term *= q / ((double)k * (double)k);
        sum += term;
        if (term < sum * 1e-17) break;
    }
    return sum;
}

extern "C" void kernel_launch(void* const* d_in, const int* in_sizes, int n_in,
                              void* d_out, int out_size, void* d_ws, size_t ws_size,
                              hipStream_t stream)
{
    const float* y_real  = (const float*)d_in[0];
    const float* y_imag  = (const float*)d_in[1];
    const float* weights = (const float*)d_in[2];
    const float* uv      = (const float*)d_in[3];
    float* out = (float*)d_out;

    char* ws = (char*)d_ws;
    float* grid = (float*)ws;                                   // 16 MB: B*K*K*2 f32
    float* G    = (float*)(ws + (size_t)16 * 1024 * 1024);      //  8 MB: B*N*K*2 f32
    float* img  = (float*)(ws + (size_t)24 * 1024 * 1024);      //  2 MB: B*N*N f32
    float* mm   = (float*)(ws + (size_t)26 * 1024 * 1024);      // 64 B

    // BETA = pi * sqrt((J/alpha*(alpha-0.5))^2 - 0.8) with alpha=2 -> sqrt(19.45)
    double beta_d = M_PI * sqrt(19.45);
    float beta = (float)beta_d;
    float inv_i0b = (float)(1.0 / i0_host(beta_d));
    float beta2 = (float)(beta_d * beta_d);

    hipMemsetAsync(grid, 0, (size_t)BB * KK * KK * 2 * sizeof(float), stream);

    grid_scatter<<<(BB * MPTS + 255) / 256, 256, 0, stream>>>(
        y_real, y_imag, weights, uv, grid, beta, inv_i0b);

    dft_rows<<<BB * 32, 256, 0, stream>>>(grid, G);

    dft_cols<<<BB * NN, 256, 0, stream>>>(G, img, beta2);

    minmax_k<<<BB, 1024, 0, stream>>>(img, mm);

    norm_k<<<(BB * NN * NN + 255) / 256, 256, 0, stream>>>(img, mm, out);
}

// Round 2
// 583.618 us; speedup vs baseline: 5.6814x; 5.6814x over previous
//
#include <hip/hip_runtime.h>
#include <math.h>

// Problem constants
#define NN 256
#define KK 512
#define JJ 6
#define BB 8
#define MPTS 100000
#define NBINS (KK * KK)
// K/(2*pi)
#define KF_SCALE 81.48733086305615f

// ---------- device helpers ----------

// Abramowitz & Stegun 9.8.1 / 9.8.2 modified Bessel I0, float
__device__ __forceinline__ float i0f_dev(float x) {
    float ax = fabsf(x);
    if (ax < 3.75f) {
        float t = x / 3.75f; t *= t;
        return 1.0f + t*(3.5156229f + t*(3.0899424f + t*(1.2067492f +
               t*(0.2659732f + t*(0.0360768f + t*0.0045813f)))));
    } else {
        float t = 3.75f / ax;
        return (expf(ax) * rsqrtf(ax)) *
               (0.39894228f + t*(0.01328592f + t*(0.00225319f + t*(-0.00157565f +
                t*(0.00916281f + t*(-0.02057706f + t*(0.02635537f +
                t*(-0.01647633f + t*0.00392377f))))))));
    }
}

// Kaiser-Bessel kernel value at distance t
__device__ __forceinline__ float kbf(float t, float beta, float inv_i0b) {
    float u = t * (1.0f / 3.0f);       // 2*t/J, J=6
    float q = fmaxf(1.0f - u * u, 0.0f);
    return i0f_dev(beta * sqrtf(q)) * inv_i0b;
}

// ---------- binning / gather kernels ----------

// Per point: fracs, pre-weighted transposed y records, bin counts.
__global__ __launch_bounds__(256) void prep_points(
    const float* __restrict__ y_real, const float* __restrict__ y_imag,
    const float* __restrict__ weights, const float* __restrict__ uv,
    float2* __restrict__ frac, float2* __restrict__ ytw, int* __restrict__ counts)
{
    int m = blockIdx.x * 256 + threadIdx.x;
    if (m >= MPTS) return;
    float kf0 = uv[2 * m]     * KF_SCALE;
    float kf1 = uv[2 * m + 1] * KF_SCALE;
    float f0 = floorf(kf0), f1 = floorf(kf1);
    frac[m] = make_float2(kf0 - f0, kf1 - f1);
    int bin = (((int)f0 & (KK - 1)) << 9) | ((int)f1 & (KK - 1));
    atomicAdd(&counts[bin], 1);
    float wm = weights[m];
#pragma unroll
    for (int b = 0; b < BB; ++b) {
        ytw[m * BB + b] = make_float2(y_real[b * MPTS + m] * wm,
                                      y_imag[b * MPTS + m] * wm);
    }
}

// Scan stage 1: 256 blocks x 1024 threads, block-local exclusive scan.
__global__ __launch_bounds__(1024) void scan1(
    const int* __restrict__ counts, int* __restrict__ offsets, int* __restrict__ bsum)
{
    __shared__ int s[1024];
    int i = blockIdx.x * 1024 + threadIdx.x;
    int v = counts[i];
    s[threadIdx.x] = v;
    for (int off = 1; off < 1024; off <<= 1) {
        __syncthreads();
        int t = (threadIdx.x >= off) ? s[threadIdx.x - off] : 0;
        __syncthreads();
        s[threadIdx.x] += t;
    }
    offsets[i] = s[threadIdx.x] - v;          // exclusive within block
    if (threadIdx.x == 1023) bsum[blockIdx.x] = s[1023];
}

// Scan stage 2: single block scans the 256 block totals (exclusive).
__global__ __launch_bounds__(256) void scan2(
    const int* __restrict__ bsum, int* __restrict__ boff)
{
    __shared__ int s[256];
    int v = bsum[threadIdx.x];
    s[threadIdx.x] = v;
    for (int off = 1; off < 256; off <<= 1) {
        __syncthreads();
        int t = (threadIdx.x >= off) ? s[threadIdx.x - off] : 0;
        __syncthreads();
        s[threadIdx.x] += t;
    }
    boff[threadIdx.x] = s[threadIdx.x] - v;
}

// Scan stage 3: add block offsets; write sentinel.
__global__ __launch_bounds__(1024) void scan3(
    int* __restrict__ offsets, const int* __restrict__ boff)
{
    int i = blockIdx.x * 1024 + threadIdx.x;
    offsets[i] += boff[blockIdx.x];
    if (i == 0) offsets[NBINS] = MPTS;
}

// Fill CSR lists; consumes counts via atomicSub (order within bin irrelevant).
__global__ __launch_bounds__(256) void fill_bins(
    const float* __restrict__ uv, const int* __restrict__ offsets,
    int* __restrict__ counts, int* __restrict__ list)
{
    int m = blockIdx.x * 256 + threadIdx.x;
    if (m >= MPTS) return;
    float kf0 = uv[2 * m]     * KF_SCALE;
    float kf1 = uv[2 * m + 1] * KF_SCALE;
    int bin = (((int)floorf(kf0) & (KK - 1)) << 9) | ((int)floorf(kf1) & (KK - 1));
    int old = atomicSub(&counts[bin], 1);
    list[offsets[bin] + old - 1] = m;
}

// One thread per grid cell: gather from 6x6 neighbor bins, all 8 batches.
__global__ __launch_bounds__(256) void gather_grid(
    const int* __restrict__ offsets, const int* __restrict__ list,
    const float2* __restrict__ frac, const float2* __restrict__ ytw,
    float* __restrict__ grid, float beta, float inv_i0b)
{
    int c = blockIdx.x * 256 + threadIdx.x;
    int c0 = c >> 9, c1 = c & (KK - 1);

    float2 acc[BB];
#pragma unroll
    for (int b = 0; b < BB; ++b) acc[b] = make_float2(0.0f, 0.0f);

    for (int j0 = 0; j0 < JJ; ++j0) {
        int o0 = j0 - 2;                       // offsets -2..3
        int r0 = (c0 - o0) & (KK - 1);
        for (int j1 = 0; j1 < JJ; ++j1) {
            int o1 = j1 - 2;
            int bin = (r0 << 9) | ((c1 - o1) & (KK - 1));
            int s = offsets[bin];
            int e = offsets[bin + 1];
            for (int p = s; p < e; ++p) {
                int m = list[p];
                float2 fr = frac[m];
                float ww = kbf((float)o0 - fr.x, beta, inv_i0b) *
                           kbf((float)o1 - fr.y, beta, inv_i0b);
                const float2* y2 = &ytw[m * BB];
#pragma unroll
                for (int b = 0; b < BB; ++b) {
                    float2 v = y2[b];
                    acc[b].x += ww * v.x;
                    acc[b].y += ww * v.y;
                }
            }
        }
    }

    float2* g2 = (float2*)grid;
#pragma unroll
    for (int b = 0; b < BB; ++b)
        g2[((size_t)b * KK + c0) * KK + c1] = acc[b];
}

// ---------- DFT / epilogue kernels (unchanged from round 0) ----------

// Stage 1: G[b][r][k2] = sum_k1 grid[b][k1][k2] * e^{+2pi i k1 x1 / 512}
__global__ __launch_bounds__(256) void dft_rows(
    const float* __restrict__ grid, float* __restrict__ G)
{
    __shared__ float twc[KK], tws[KK];
    int b = blockIdx.x >> 5;
    int r0 = (blockIdx.x & 31) * 8;
    int t = threadIdx.x;

    for (int p = t; p < KK; p += 256) {
        float ang = (float)(2.0 * M_PI / (double)KK) * (float)p;
        float s, c; sincosf(ang, &s, &c);
        twc[p] = c; tws[p] = s;
    }
    __syncthreads();

    int x1[8], ph[8];
    float accR0[8], accI0[8], accR1[8], accI1[8];
#pragma unroll
    for (int rr = 0; rr < 8; ++rr) {
        x1[rr] = (384 + r0 + rr) & (KK - 1);
        ph[rr] = 0;
        accR0[rr] = accI0[rr] = accR1[rr] = accI1[rr] = 0.0f;
    }

    const float2* g2 = (const float2*)grid + (size_t)b * KK * KK;
    for (int k1 = 0; k1 < KK; ++k1) {
        float2 ga = g2[k1 * KK + t];
        float2 gb = g2[k1 * KK + t + 256];
#pragma unroll
        for (int rr = 0; rr < 8; ++rr) {
            int p = ph[rr];
            float c = twc[p], s = tws[p];
            accR0[rr] += ga.x * c - ga.y * s;
            accI0[rr] += ga.x * s + ga.y * c;
            accR1[rr] += gb.x * c - gb.y * s;
            accI1[rr] += gb.x * s + gb.y * c;
            ph[rr] = (p + x1[rr]) & (KK - 1);
        }
    }

    float2* Gout = (float2*)G;
#pragma unroll
    for (int rr = 0; rr < 8; ++rr) {
        size_t base = ((size_t)b * NN + (r0 + rr)) * KK;
        Gout[base + t]       = make_float2(accR0[rr], accI0[rr]);
        Gout[base + t + 256] = make_float2(accR1[rr], accI1[rr]);
    }
}

// Stage 2: img[b][r][s] = Re( sum_k2 G[b][r][k2] e^{+2pi i k2 x2/512} ) / K^2 / apod
__global__ __launch_bounds__(256) void dft_cols(
    const float* __restrict__ G, float* __restrict__ img, float beta2)
{
    __shared__ float twc[KK], tws[KK], gr[KK], gi[KK];
    int b = blockIdx.x >> 8;
    int r = blockIdx.x & 255;
    int t = threadIdx.x;

    const float2* Grow = (const float2*)G + ((size_t)b * NN + r) * KK;
    for (int p = t; p < KK; p += 256) {
        float ang = (float)(2.0 * M_PI / (double)KK) * (float)p;
        float s, c; sincosf(ang, &s, &c);
        twc[p] = c; tws[p] = s;
        float2 g = Grow[p];
        gr[p] = g.x; gi[p] = g.y;
    }
    __syncthreads();

    int x2 = (384 + t) & (KK - 1);
    float acc = 0.0f;
    int p = 0;
    for (int k2 = 0; k2 < KK; ++k2) {
        float c = twc[p], s = tws[p];
        acc += gr[k2] * c - gi[k2] * s;
        p = (p + x2) & (KK - 1);
    }

    const float XF = (float)(M_PI * (double)JJ / (double)KK);
    float nr = (float)(r - 128), ns = (float)(t - 128);
    float xfr = XF * nr, xfs = XF * ns;
    float ar_ = beta2 - xfr * xfr;
    float as_ = beta2 - xfs * xfs;
    float sr = sqrtf(ar_), ss = sqrtf(as_);
    float dr = sinhf(sr) / sr;
    float ds = sinhf(ss) / ss;

    float val = acc * (1.0f / ((float)KK * (float)KK)) / (dr * ds);
    img[((size_t)b * NN + r) * NN + t] = val;
}

// Per-batch min/max: one block per batch.
__global__ __launch_bounds__(1024) void minmax_k(
    const float* __restrict__ img, float* __restrict__ mm)
{
    int b = blockIdx.x;
    const float* p = img + (size_t)b * NN * NN;
    float lmin = 1e30f, lmax = -1e30f;
    for (int i = threadIdx.x; i < NN * NN; i += 1024) {
        float v = p[i];
        lmin = fminf(lmin, v);
        lmax = fmaxf(lmax, v);
    }
#pragma unroll
    for (int off = 32; off >= 1; off >>= 1) {
        lmin = fminf(lmin, __shfl_down(lmin, off));
        lmax = fmaxf(lmax, __shfl_down(lmax, off));
    }
    __shared__ float smin[16], smax[16];
    int wave = threadIdx.x >> 6;
    if ((threadIdx.x & 63) == 0) { smin[wave] = lmin; smax[wave] = lmax; }
    __syncthreads();
    if (threadIdx.x == 0) {
        float mn = smin[0], mx = smax[0];
        for (int w = 1; w < 16; ++w) {
            mn = fminf(mn, smin[w]);
            mx = fmaxf(mx, smax[w]);
        }
        mm[2 * b] = mn;
        mm[2 * b + 1] = mx;
    }
}

__global__ __launch_bounds__(256) void norm_k(
    const float* __restrict__ img, const float* __restrict__ mm,
    float* __restrict__ out)
{
    int i = blockIdx.x * 256 + threadIdx.x;
    if (i >= BB * NN * NN) return;
    int b = i >> 16;
    float mn = mm[2 * b], mx = mm[2 * b + 1];
    out[i] = (img[i] - mn) / (mx - mn);
}

// ---------- host ----------

static double i0_host(double x) {
    double sum = 1.0, term = 1.0;
    double q = x * x * 0.25;
    for (int k = 1; k < 80; ++k) {
        term *= q / ((double)k * (double)k);
        sum += term;
        if (term < sum * 1e-17) break;
    }
    return sum;
}

extern "C" void kernel_launch(void* const* d_in, const int* in_sizes, int n_in,
                              void* d_out, int out_size, void* d_ws, size_t ws_size,
                              hipStream_t stream)
{
    const float* y_real  = (const float*)d_in[0];
    const float* y_imag  = (const float*)d_in[1];
    const float* weights = (const float*)d_in[2];
    const float* uv      = (const float*)d_in[3];
    float* out = (float*)d_out;

    char* ws = (char*)d_ws;
    // Live ranges allow aliasing (total footprint ~25.3 MB):
    //  grid [0,16M)            : gather -> dft_rows
    //  A    [16M,~26.5M)       : prep -> gather (binning data, dead after gather)
    //  G    [16M,24M)          : dft_rows -> dft_cols (over dead A)
    //  img  [0,2M), mm [2M,..) : dft_cols -> norm (over dead grid)
    float*  grid    = (float*)ws;                                  // 16,777,216 B
    char*   A       = ws + (size_t)16 * 1024 * 1024;
    float2* frac    = (float2*)(A);                                // 800,000 B
    float2* ytw     = (float2*)(A + 800000);                       // 6,400,000 B
    int*    list    = (int*)(A + 7200000);                         // 400,000 B
    int*    counts  = (int*)(A + 7600000);                         // 1,048,576 B
    int*    offsets = (int*)(A + 8648576);                         // 1,048,580 B (+pad)
    int*    bsum    = (int*)(A + 9697168);                         // 1,024 B
    int*    boff    = (int*)(A + 9698192);                         // 1,024 B
    float*  G       = (float*)(ws + (size_t)16 * 1024 * 1024);     // 8,388,608 B
    float*  img     = (float*)ws;                                  // 2,097,152 B
    float*  mm      = (float*)(ws + 2097152);                      // 64 B

    double beta_d = M_PI * sqrt(19.45);   // BETA with alpha=2
    float beta = (float)beta_d;
    float inv_i0b = (float)(1.0 / i0_host(beta_d));
    float beta2 = (float)(beta_d * beta_d);

    hipMemsetAsync(counts, 0, NBINS * sizeof(int), stream);

    prep_points<<<(MPTS + 255) / 256, 256, 0, stream>>>(
        y_real, y_imag, weights, uv, frac, ytw, counts);

    scan1<<<256, 1024, 0, stream>>>(counts, offsets, bsum);
    scan2<<<1, 256, 0, stream>>>(bsum, boff);
    scan3<<<256, 1024, 0, stream>>>(offsets, boff);

    fill_bins<<<(MPTS + 255) / 256, 256, 0, stream>>>(uv, offsets, counts, list);

    gather_grid<<<NBINS / 256, 256, 0, stream>>>(
        offsets, list, frac, ytw, grid, beta, inv_i0b);

    dft_rows<<<BB * 32, 256, 0, stream>>>(grid, G);

    dft_cols<<<BB * NN, 256, 0, stream>>>(G, img, beta2);

    minmax_k<<<BB, 1024, 0, stream>>>(img, mm);

    norm_k<<<(BB * NN * NN + 255) / 256, 256, 0, stream>>>(img, mm, out);
}

// Round 3
// 460.608 us; speedup vs baseline: 7.1987x; 1.2671x over previous
//
#include <hip/hip_runtime.h>
#include <math.h>

// Problem constants
#define NN 256
#define KK 512
#define JJ 6
#define BB 8
#define MPTS 100000
#define NBINS (KK * KK)
// K/(2*pi)
#define KF_SCALE 81.48733086305615f

// ---------- device helpers ----------

// Abramowitz & Stegun 9.8.1 / 9.8.2 modified Bessel I0, float
__device__ __forceinline__ float i0f_dev(float x) {
    float ax = fabsf(x);
    if (ax < 3.75f) {
        float t = x / 3.75f; t *= t;
        return 1.0f + t*(3.5156229f + t*(3.0899424f + t*(1.2067492f +
               t*(0.2659732f + t*(0.0360768f + t*0.0045813f)))));
    } else {
        float t = 3.75f / ax;
        return (expf(ax) * rsqrtf(ax)) *
               (0.39894228f + t*(0.01328592f + t*(0.00225319f + t*(-0.00157565f +
                t*(0.00916281f + t*(-0.02057706f + t*(0.02635537f +
                t*(-0.01647633f + t*0.00392377f))))))));
    }
}

// Kaiser-Bessel kernel value at distance t
__device__ __forceinline__ float kbf(float t, float beta, float inv_i0b) {
    float u = t * (1.0f / 3.0f);       // 2*t/J, J=6
    float q = fmaxf(1.0f - u * u, 0.0f);
    return i0f_dev(beta * sqrtf(q)) * inv_i0b;
}

// ---------- binning / gather kernels ----------

// Per point: fracs, pre-weighted transposed y records, bin counts.
__global__ __launch_bounds__(256) void prep_points(
    const float* __restrict__ y_real, const float* __restrict__ y_imag,
    const float* __restrict__ weights, const float* __restrict__ uv,
    float2* __restrict__ frac, float2* __restrict__ ytw, int* __restrict__ counts)
{
    int m = blockIdx.x * 256 + threadIdx.x;
    if (m >= MPTS) return;
    float kf0 = uv[2 * m]     * KF_SCALE;
    float kf1 = uv[2 * m + 1] * KF_SCALE;
    float f0 = floorf(kf0), f1 = floorf(kf1);
    frac[m] = make_float2(kf0 - f0, kf1 - f1);
    int bin = (((int)f0 & (KK - 1)) << 9) | ((int)f1 & (KK - 1));
    atomicAdd(&counts[bin], 1);
    float wm = weights[m];
#pragma unroll
    for (int b = 0; b < BB; ++b) {
        ytw[m * BB + b] = make_float2(y_real[b * MPTS + m] * wm,
                                      y_imag[b * MPTS + m] * wm);
    }
}

// Scan stage 1: 256 blocks x 1024 threads, block-local exclusive scan.
__global__ __launch_bounds__(1024) void scan1(
    const int* __restrict__ counts, int* __restrict__ offsets, int* __restrict__ bsum)
{
    __shared__ int s[1024];
    int i = blockIdx.x * 1024 + threadIdx.x;
    int v = counts[i];
    s[threadIdx.x] = v;
    for (int off = 1; off < 1024; off <<= 1) {
        __syncthreads();
        int t = (threadIdx.x >= off) ? s[threadIdx.x - off] : 0;
        __syncthreads();
        s[threadIdx.x] += t;
    }
    offsets[i] = s[threadIdx.x] - v;          // exclusive within block
    if (threadIdx.x == 1023) bsum[blockIdx.x] = s[1023];
}

// Scan stage 2: single block scans the 256 block totals (exclusive).
__global__ __launch_bounds__(256) void scan2(
    const int* __restrict__ bsum, int* __restrict__ boff)
{
    __shared__ int s[256];
    int v = bsum[threadIdx.x];
    s[threadIdx.x] = v;
    for (int off = 1; off < 256; off <<= 1) {
        __syncthreads();
        int t = (threadIdx.x >= off) ? s[threadIdx.x - off] : 0;
        __syncthreads();
        s[threadIdx.x] += t;
    }
    boff[threadIdx.x] = s[threadIdx.x] - v;
}

// Scan stage 3: add block offsets; write sentinel.
__global__ __launch_bounds__(1024) void scan3(
    int* __restrict__ offsets, const int* __restrict__ boff)
{
    int i = blockIdx.x * 1024 + threadIdx.x;
    offsets[i] += boff[blockIdx.x];
    if (i == 0) offsets[NBINS] = MPTS;
}

// Fill CSR lists; consumes counts via atomicSub (order within bin irrelevant).
__global__ __launch_bounds__(256) void fill_bins(
    const float* __restrict__ uv, const int* __restrict__ offsets,
    int* __restrict__ counts, int* __restrict__ list)
{
    int m = blockIdx.x * 256 + threadIdx.x;
    if (m >= MPTS) return;
    float kf0 = uv[2 * m]     * KF_SCALE;
    float kf1 = uv[2 * m + 1] * KF_SCALE;
    int bin = (((int)floorf(kf0) & (KK - 1)) << 9) | ((int)floorf(kf1) & (KK - 1));
    int old = atomicSub(&counts[bin], 1);
    list[offsets[bin] + old - 1] = m;
}

// One thread per grid cell: gather from 6x6 neighbor bins, all 8 batches.
__global__ __launch_bounds__(256) void gather_grid(
    const int* __restrict__ offsets, const int* __restrict__ list,
    const float2* __restrict__ frac, const float2* __restrict__ ytw,
    float* __restrict__ grid, float beta, float inv_i0b)
{
    int c = blockIdx.x * 256 + threadIdx.x;
    int c0 = c >> 9, c1 = c & (KK - 1);

    float2 acc[BB];
#pragma unroll
    for (int b = 0; b < BB; ++b) acc[b] = make_float2(0.0f, 0.0f);

    for (int j0 = 0; j0 < JJ; ++j0) {
        int o0 = j0 - 2;                       // offsets -2..3
        int r0 = (c0 - o0) & (KK - 1);
        for (int j1 = 0; j1 < JJ; ++j1) {
            int o1 = j1 - 2;
            int bin = (r0 << 9) | ((c1 - o1) & (KK - 1));
            int s = offsets[bin];
            int e = offsets[bin + 1];
            for (int p = s; p < e; ++p) {
                int m = list[p];
                float2 fr = frac[m];
                float ww = kbf((float)o0 - fr.x, beta, inv_i0b) *
                           kbf((float)o1 - fr.y, beta, inv_i0b);
                const float2* y2 = &ytw[m * BB];
#pragma unroll
                for (int b = 0; b < BB; ++b) {
                    float2 v = y2[b];
                    acc[b].x += ww * v.x;
                    acc[b].y += ww * v.y;
                }
            }
        }
    }

    float2* g2 = (float2*)grid;
#pragma unroll
    for (int b = 0; b < BB; ++b)
        g2[((size_t)b * KK + c0) * KK + c1] = acc[b];
}

// ---------- DFT kernels (v2: register rotation recurrence, no LDS twiddles) ----------

// Stage 1: G[b][r][k2] = sum_k1 grid[b][k1][k2] * e^{+2pi i k1 x1 / 512},
// x1 = (384+r)&511. 512 blocks: b = blk&7 (XCD-swizzle), 4 rows each.
// Each thread owns k2 = {t, t+256}, twiddles via complex rotation in regs.
__global__ __launch_bounds__(256) void dft_rows(
    const float* __restrict__ grid, float* __restrict__ G)
{
    int b  = blockIdx.x & 7;              // same batch -> same XCD (L2 locality)
    int r0 = (blockIdx.x >> 3) * 4;
    int t  = threadIdx.x;

    float cr[4], sr[4], c1[4], s1[4];
    float aR0[4], aI0[4], aR1[4], aI1[4];
#pragma unroll
    for (int rr = 0; rr < 4; ++rr) {
        int x1 = (384 + r0 + rr) & (KK - 1);
        float ang = (float)(2.0 * M_PI / (double)KK) * (float)x1;
        sincosf(ang, &s1[rr], &c1[rr]);
        cr[rr] = 1.0f; sr[rr] = 0.0f;
        aR0[rr] = aI0[rr] = aR1[rr] = aI1[rr] = 0.0f;
    }

    const float2* g2 = (const float2*)grid + (size_t)b * KK * KK;
    for (int k1 = 0; k1 < KK; ++k1) {
        float2 ga = g2[k1 * KK + t];
        float2 gb = g2[k1 * KK + t + 256];
#pragma unroll
        for (int rr = 0; rr < 4; ++rr) {
            float c = cr[rr], s = sr[rr];
            aR0[rr] += ga.x * c - ga.y * s;
            aI0[rr] += ga.x * s + ga.y * c;
            aR1[rr] += gb.x * c - gb.y * s;
            aI1[rr] += gb.x * s + gb.y * c;
            cr[rr] = c * c1[rr] - s * s1[rr];   // rotate by e^{i*2pi*x1/512}
            sr[rr] = c * s1[rr] + s * c1[rr];
        }
    }

    float2* Gout = (float2*)G;
#pragma unroll
    for (int rr = 0; rr < 4; ++rr) {
        size_t base = ((size_t)b * NN + (r0 + rr)) * KK;
        Gout[base + t]       = make_float2(aR0[rr], aI0[rr]);
        Gout[base + t + 256] = make_float2(aR1[rr], aI1[rr]);
    }
}

// Stage 2: img[b][r][s] = Re( sum_k2 G[b][r][k2] e^{+2pi i k2 x2/512} ) / K^2 / apod
// 2048 blocks (b = blk&7), row staged in LDS (broadcast reads), rotation twiddles.
__global__ __launch_bounds__(256) void dft_cols(
    const float* __restrict__ G, float* __restrict__ img, float beta2)
{
    __shared__ float gr[KK], gi[KK];
    int b = blockIdx.x & 7;
    int r = blockIdx.x >> 3;
    int t = threadIdx.x;

    const float2* Grow = (const float2*)G + ((size_t)b * NN + r) * KK;
    for (int p = t; p < KK; p += 256) {
        float2 g = Grow[p];
        gr[p] = g.x; gi[p] = g.y;
    }
    __syncthreads();

    int x2 = (384 + t) & (KK - 1);
    float ang = (float)(2.0 * M_PI / (double)KK) * (float)x2;
    float c1, s1; sincosf(ang, &s1, &c1);
    float c = 1.0f, s = 0.0f, acc = 0.0f;
    for (int k2 = 0; k2 < KK; ++k2) {
        acc += gr[k2] * c - gi[k2] * s;      // LDS broadcast: all lanes same addr
        float cn = c * c1 - s * s1;
        s = c * s1 + s * c1;
        c = cn;
    }

    const float XF = (float)(M_PI * (double)JJ / (double)KK);
    float nr = (float)(r - 128), ns = (float)(t - 128);
    float xfr = XF * nr, xfs = XF * ns;
    float ar_ = beta2 - xfr * xfr;
    float as_ = beta2 - xfs * xfs;
    float srq = sqrtf(ar_), ssq = sqrtf(as_);
    float dr = sinhf(srq) / srq;
    float ds = sinhf(ssq) / ssq;

    float val = acc * (1.0f / ((float)KK * (float)KK)) / (dr * ds);
    img[((size_t)b * NN + r) * NN + t] = val;
}

// Per-batch min/max: one block per batch.
__global__ __launch_bounds__(1024) void minmax_k(
    const float* __restrict__ img, float* __restrict__ mm)
{
    int b = blockIdx.x;
    const float* p = img + (size_t)b * NN * NN;
    float lmin = 1e30f, lmax = -1e30f;
    for (int i = threadIdx.x; i < NN * NN; i += 1024) {
        float v = p[i];
        lmin = fminf(lmin, v);
        lmax = fmaxf(lmax, v);
    }
#pragma unroll
    for (int off = 32; off >= 1; off >>= 1) {
        lmin = fminf(lmin, __shfl_down(lmin, off));
        lmax = fmaxf(lmax, __shfl_down(lmax, off));
    }
    __shared__ float smin[16], smax[16];
    int wave = threadIdx.x >> 6;
    if ((threadIdx.x & 63) == 0) { smin[wave] = lmin; smax[wave] = lmax; }
    __syncthreads();
    if (threadIdx.x == 0) {
        float mn = smin[0], mx = smax[0];
        for (int w = 1; w < 16; ++w) {
            mn = fminf(mn, smin[w]);
            mx = fmaxf(mx, smax[w]);
        }
        mm[2 * b] = mn;
        mm[2 * b + 1] = mx;
    }
}

__global__ __launch_bounds__(256) void norm_k(
    const float* __restrict__ img, const float* __restrict__ mm,
    float* __restrict__ out)
{
    int i = blockIdx.x * 256 + threadIdx.x;
    if (i >= BB * NN * NN) return;
    int b = i >> 16;
    float mn = mm[2 * b], mx = mm[2 * b + 1];
    out[i] = (img[i] - mn) / (mx - mn);
}

// ---------- host ----------

static double i0_host(double x) {
    double sum = 1.0, term = 1.0;
    double q = x * x * 0.25;
    for (int k = 1; k < 80; ++k) {
        term *= q / ((double)k * (double)k);
        sum += term;
        if (term < sum * 1e-17) break;
    }
    return sum;
}

extern "C" void kernel_launch(void* const* d_in, const int* in_sizes, int n_in,
                              void* d_out, int out_size, void* d_ws, size_t ws_size,
                              hipStream_t stream)
{
    const float* y_real  = (const float*)d_in[0];
    const float* y_imag  = (const float*)d_in[1];
    const float* weights = (const float*)d_in[2];
    const float* uv      = (const float*)d_in[3];
    float* out = (float*)d_out;

    char* ws = (char*)d_ws;
    // Live ranges allow aliasing (total footprint ~25.3 MB):
    //  grid [0,16M)            : gather -> dft_rows
    //  A    [16M,~26.5M)       : prep -> gather (binning data, dead after gather)
    //  G    [16M,24M)          : dft_rows -> dft_cols (over dead A)
    //  img  [0,2M), mm [2M,..) : dft_cols -> norm (over dead grid)
    float*  grid    = (float*)ws;                                  // 16,777,216 B
    char*   A       = ws + (size_t)16 * 1024 * 1024;
    float2* frac    = (float2*)(A);                                // 800,000 B
    float2* ytw     = (float2*)(A + 800000);                       // 6,400,000 B
    int*    list    = (int*)(A + 7200000);                         // 400,000 B
    int*    counts  = (int*)(A + 7600000);                         // 1,048,576 B
    int*    offsets = (int*)(A + 8648576);                         // 1,048,580 B (+pad)
    int*    bsum    = (int*)(A + 9697168);                         // 1,024 B
    int*    boff    = (int*)(A + 9698192);                         // 1,024 B
    float*  G       = (float*)(ws + (size_t)16 * 1024 * 1024);     // 8,388,608 B
    float*  img     = (float*)ws;                                  // 2,097,152 B
    float*  mm      = (float*)(ws + 2097152);                      // 64 B

    double beta_d = M_PI * sqrt(19.45);   // BETA with alpha=2
    float beta = (float)beta_d;
    float inv_i0b = (float)(1.0 / i0_host(beta_d));
    float beta2 = (float)(beta_d * beta_d);

    hipMemsetAsync(counts, 0, NBINS * sizeof(int), stream);

    prep_points<<<(MPTS + 255) / 256, 256, 0, stream>>>(
        y_real, y_imag, weights, uv, frac, ytw, counts);

    scan1<<<256, 1024, 0, stream>>>(counts, offsets, bsum);
    scan2<<<1, 256, 0, stream>>>(bsum, boff);
    scan3<<<256, 1024, 0, stream>>>(offsets, boff);

    fill_bins<<<(MPTS + 255) / 256, 256, 0, stream>>>(uv, offsets, counts, list);

    gather_grid<<<NBINS / 256, 256, 0, stream>>>(
        offsets, list, frac, ytw, grid, beta, inv_i0b);

    dft_rows<<<512, 256, 0, stream>>>(grid, G);

    dft_cols<<<BB * NN, 256, 0, stream>>>(G, img, beta2);

    minmax_k<<<BB, 1024, 0, stream>>>(img, mm);

    norm_k<<<(BB * NN * NN + 255) / 256, 256, 0, stream>>>(img, mm, out);
}

// Round 4
// 244.617 us; speedup vs baseline: 13.5550x; 1.8830x over previous
//
#include <hip/hip_runtime.h>
#include <math.h>

// Problem constants
#define NN 256
#define KK 512
#define JJ 6
#define BB 8
#define MPTS 100000
#define NBINS (KK * KK)
// K/(2*pi)
#define KF_SCALE 81.48733086305615f

// ---------- device helpers ----------

// Abramowitz & Stegun 9.8.1 / 9.8.2 modified Bessel I0, float
__device__ __forceinline__ float i0f_dev(float x) {
    float ax = fabsf(x);
    if (ax < 3.75f) {
        float t = x / 3.75f; t *= t;
        return 1.0f + t*(3.5156229f + t*(3.0899424f + t*(1.2067492f +
               t*(0.2659732f + t*(0.0360768f + t*0.0045813f)))));
    } else {
        float t = 3.75f / ax;
        return (expf(ax) * rsqrtf(ax)) *
               (0.39894228f + t*(0.01328592f + t*(0.00225319f + t*(-0.00157565f +
                t*(0.00916281f + t*(-0.02057706f + t*(0.02635537f +
                t*(-0.01647633f + t*0.00392377f))))))));
    }
}

__device__ __forceinline__ float kbf(float t, float beta, float inv_i0b) {
    float u = t * (1.0f / 3.0f);       // 2*t/J, J=6
    float q = fmaxf(1.0f - u * u, 0.0f);
    return i0f_dev(beta * sqrtf(q)) * inv_i0b;
}

// order-preserving float<->uint for atomic min/max
__device__ __forceinline__ unsigned fkey(float f) {
    unsigned u = __float_as_uint(f);
    return (u & 0x80000000u) ? ~u : (u | 0x80000000u);
}
__device__ __forceinline__ float funkey(unsigned k) {
    unsigned u = (k & 0x80000000u) ? (k & 0x7FFFFFFFu) : ~k;
    return __uint_as_float(u);
}

// ---------- binning kernels ----------

__global__ __launch_bounds__(256) void prep_points(
    const float* __restrict__ y_real, const float* __restrict__ y_imag,
    const float* __restrict__ weights, const float* __restrict__ uv,
    float2* __restrict__ frac, float2* __restrict__ ytw, int* __restrict__ counts)
{
    int m = blockIdx.x * 256 + threadIdx.x;
    if (m >= MPTS) return;
    float kf0 = uv[2 * m]     * KF_SCALE;
    float kf1 = uv[2 * m + 1] * KF_SCALE;
    float f0 = floorf(kf0), f1 = floorf(kf1);
    frac[m] = make_float2(kf0 - f0, kf1 - f1);
    int bin = (((int)f0 & (KK - 1)) << 9) | ((int)f1 & (KK - 1));
    atomicAdd(&counts[bin], 1);
    float wm = weights[m];
#pragma unroll
    for (int b = 0; b < BB; ++b) {
        ytw[m * BB + b] = make_float2(y_real[b * MPTS + m] * wm,
                                      y_imag[b * MPTS + m] * wm);
    }
}

__global__ __launch_bounds__(1024) void scan1(
    const int* __restrict__ counts, int* __restrict__ offsets, int* __restrict__ bsum)
{
    __shared__ int s[1024];
    int i = blockIdx.x * 1024 + threadIdx.x;
    int v = counts[i];
    s[threadIdx.x] = v;
    for (int off = 1; off < 1024; off <<= 1) {
        __syncthreads();
        int t = (threadIdx.x >= off) ? s[threadIdx.x - off] : 0;
        __syncthreads();
        s[threadIdx.x] += t;
    }
    offsets[i] = s[threadIdx.x] - v;
    if (threadIdx.x == 1023) bsum[blockIdx.x] = s[1023];
}

__global__ __launch_bounds__(256) void scan2(
    const int* __restrict__ bsum, int* __restrict__ boff)
{
    __shared__ int s[256];
    int v = bsum[threadIdx.x];
    s[threadIdx.x] = v;
    for (int off = 1; off < 256; off <<= 1) {
        __syncthreads();
        int t = (threadIdx.x >= off) ? s[threadIdx.x - off] : 0;
        __syncthreads();
        s[threadIdx.x] += t;
    }
    boff[threadIdx.x] = s[threadIdx.x] - v;
}

__global__ __launch_bounds__(1024) void scan3(
    int* __restrict__ offsets, const int* __restrict__ boff)
{
    int i = blockIdx.x * 1024 + threadIdx.x;
    offsets[i] += boff[blockIdx.x];
    if (i == 0) offsets[NBINS] = MPTS;
}

__global__ __launch_bounds__(256) void fill_bins(
    const float* __restrict__ uv, const int* __restrict__ offsets,
    int* __restrict__ counts, int* __restrict__ list)
{
    int m = blockIdx.x * 256 + threadIdx.x;
    if (m >= MPTS) return;
    float kf0 = uv[2 * m]     * KF_SCALE;
    float kf1 = uv[2 * m + 1] * KF_SCALE;
    int bin = (((int)floorf(kf0) & (KK - 1)) << 9) | ((int)floorf(kf1) & (KK - 1));
    int old = atomicSub(&counts[bin], 1);
    list[offsets[bin] + old - 1] = m;
}

// ---------- gather v2: contiguous CSR ranges per row ----------

__global__ __launch_bounds__(256) void gather_grid(
    const int* __restrict__ offsets, const int* __restrict__ list,
    const float2* __restrict__ frac, const float2* __restrict__ ytw,
    float* __restrict__ grid, float beta, float inv_i0b)
{
    int c = blockIdx.x * 256 + threadIdx.x;
    int c0 = c >> 9, c1 = c & (KK - 1);

    float2 acc[BB];
#pragma unroll
    for (int b = 0; b < BB; ++b) acc[b] = make_float2(0.0f, 0.0f);

    bool fast = (c1 >= 3) && (c1 <= 509);

    for (int j0 = 0; j0 < JJ; ++j0) {
        int o0 = j0 - 2;
        float fo0 = (float)o0;
        int rb = ((c0 - o0) & (KK - 1)) << 9;
        if (fast) {
            // bins [c1-3, c1+2] are CSR-contiguous: one range, track o1 by compares
            int base = rb + c1 - 3;
            int e0 = offsets[base];
            int e1 = offsets[base + 1];
            int e2 = offsets[base + 2];
            int e3 = offsets[base + 3];
            int e4 = offsets[base + 4];
            int e5 = offsets[base + 5];
            int e6 = offsets[base + 6];
            for (int p = e0; p < e6; ++p) {
                int m = list[p];
                float2 fr = frac[m];
                int jc = (p >= e1) + (p >= e2) + (p >= e3) + (p >= e4) + (p >= e5);
                float o1 = (float)(3 - jc);
                float ww = kbf(fo0 - fr.x, beta, inv_i0b) *
                           kbf(o1  - fr.y, beta, inv_i0b);
                const float2* y2 = &ytw[m * BB];
#pragma unroll
                for (int b = 0; b < BB; ++b) {
                    float2 v = y2[b];
                    acc[b].x += ww * v.x;
                    acc[b].y += ww * v.y;
                }
            }
        } else {
            for (int j1 = 0; j1 < JJ; ++j1) {
                int o1 = j1 - 2;
                int bin = rb | ((c1 - o1) & (KK - 1));
                int s = offsets[bin];
                int e = offsets[bin + 1];
                float fo1 = (float)o1;
                for (int p = s; p < e; ++p) {
                    int m = list[p];
                    float2 fr = frac[m];
                    float ww = kbf(fo0 - fr.x, beta, inv_i0b) *
                               kbf(fo1 - fr.y, beta, inv_i0b);
                    const float2* y2 = &ytw[m * BB];
#pragma unroll
                    for (int b = 0; b < BB; ++b) {
                        float2 v = y2[b];
                        acc[b].x += ww * v.x;
                        acc[b].y += ww * v.y;
                    }
                }
            }
        }
    }

    float2* g2 = (float2*)grid;
#pragma unroll
    for (int b = 0; b < BB; ++b)
        g2[((size_t)b * KK + c0) * KK + c1] = acc[b];
}

// ---------- FFT kernels (radix-2 DIT in LDS, +i sign = inverse transform) ----------

// fft1: 512-pt FFT over k1 for 8 k2-columns per block. 512 blocks (b = blk&7),
// 512 threads. Output: G[b][r][k2] = X[(384+r)&511], r in [0,256).
__global__ __launch_bounds__(512) void fft1(
    const float2* __restrict__ grid2, float2* __restrict__ Gout)
{
    __shared__ float2 data[KK][9];    // [idx][col], pad 9 breaks bank conflicts
    __shared__ float2 tw[256];
    int b = blockIdx.x & 7;
    int k2base = (blockIdx.x >> 3) << 3;
    int t = threadIdx.x;
    int col = t & 7;
    int u = t >> 3;                   // [0,64)

    if (t < 256) {
        float ang = (float)(2.0 * M_PI / 512.0) * (float)t;
        float s, c; sincosf(ang, &s, &c);
        tw[t] = make_float2(c, s);
    }

    const float2* gb = grid2 + (size_t)b * (KK * KK);
#pragma unroll
    for (int pass = 0; pass < 8; ++pass) {
        int k1 = (pass << 6) + u;
        float2 v = gb[k1 * KK + k2base + col];
        data[__brev((unsigned)k1) >> 23][col] = v;
    }
    __syncthreads();

#pragma unroll
    for (int s = 0; s < 9; ++s) {
        int half = 1 << s;
#pragma unroll
        for (int q = 0; q < 4; ++q) {
            int i = (q << 6) + u;                       // [0,256)
            int j = i & (half - 1);
            int idx1 = ((i >> s) << (s + 1)) + j;
            int idx2 = idx1 + half;
            float2 w = tw[j << (8 - s)];
            float2 d1 = data[idx1][col];
            float2 d2 = data[idx2][col];
            float2 tt = make_float2(w.x * d2.x - w.y * d2.y,
                                    w.x * d2.y + w.y * d2.x);
            data[idx1][col] = make_float2(d1.x + tt.x, d1.y + tt.y);
            data[idx2][col] = make_float2(d1.x - tt.x, d1.y - tt.y);
        }
        __syncthreads();
    }

#pragma unroll
    for (int pass = 0; pass < 4; ++pass) {
        int r = (pass << 6) + u;
        int x = (384 + r) & (KK - 1);
        Gout[((size_t)(b << 8) + r) * KK + k2base + col] = data[x][col];
    }
}

// fft2: 512-pt FFT over k2 for 4 (b,r)-rows per block + apod epilogue.
// 512 blocks, 256 threads. img[b][r][s] = Re(X[(384+s)&511]) / K^2 / apod.
__global__ __launch_bounds__(256) void fft2(
    const float2* __restrict__ G, float* __restrict__ img, float beta2)
{
    __shared__ float2 data[KK][5];    // [idx][row], pad 5
    __shared__ float2 tw[256];
    int t = threadIdx.x;
    int rowbase = blockIdx.x << 2;    // global row = b*256 + r
    int lrow = t >> 6;                // [0,4): one wave per row on load
    int lk = t & 63;
    int col = t & 3;                  // butterfly-phase row
    int u = t >> 2;                   // [0,64)

    if (t < 256) {
        float ang = (float)(2.0 * M_PI / 512.0) * (float)t;
        float s, c; sincosf(ang, &s, &c);
        tw[t] = make_float2(c, s);
    }

    const float2* Grow = G + (size_t)(rowbase + lrow) * KK;
#pragma unroll
    for (int pass = 0; pass < 8; ++pass) {
        int k2 = (pass << 6) + lk;
        data[__brev((unsigned)k2) >> 23][lrow] = Grow[k2];
    }
    __syncthreads();

#pragma unroll
    for (int s = 0; s < 9; ++s) {
        int half = 1 << s;
#pragma unroll
        for (int q = 0; q < 4; ++q) {
            int i = (q << 6) + u;
            int j = i & (half - 1);
            int idx1 = ((i >> s) << (s + 1)) + j;
            int idx2 = idx1 + half;
            float2 w = tw[j << (8 - s)];
            float2 d1 = data[idx1][col];
            float2 d2 = data[idx2][col];
            float2 tt = make_float2(w.x * d2.x - w.y * d2.y,
                                    w.x * d2.y + w.y * d2.x);
            data[idx1][col] = make_float2(d1.x + tt.x, d1.y + tt.y);
            data[idx2][col] = make_float2(d1.x - tt.x, d1.y - tt.y);
        }
        __syncthreads();
    }

    int grow = rowbase + lrow;
    int r = grow & (NN - 1);
    const float XF = (float)(M_PI * (double)JJ / (double)KK);
    float nr = (float)(r - 128);
    float xfr = XF * nr;
    float arq = beta2 - xfr * xfr;
    float srq = sqrtf(arq);
    float dr = sinhf(srq) / srq;

#pragma unroll
    for (int pass = 0; pass < 4; ++pass) {
        int s2 = (pass << 6) + lk;
        int x = (384 + s2) & (KK - 1);
        float val = data[x][lrow].x;
        float ns = (float)(s2 - 128);
        float xfs = XF * ns;
        float asq = beta2 - xfs * xfs;
        float ssq = sqrtf(asq);
        float ds = sinhf(ssq) / ssq;
        img[(size_t)grow * NN + s2] = val * (1.0f / ((float)KK * (float)KK)) / (dr * ds);
    }
}

// ---------- min/max + normalize ----------

__global__ __launch_bounds__(256) void minmax2(
    const float* __restrict__ img, unsigned* __restrict__ mmin, unsigned* __restrict__ mmax)
{
    int b = blockIdx.x >> 5;
    int chunk = blockIdx.x & 31;
    const float* p = img + (size_t)b * NN * NN + chunk * 2048;
    float lmin = 1e30f, lmax = -1e30f;
#pragma unroll
    for (int i = 0; i < 8; ++i) {
        float v = p[i * 256 + threadIdx.x];
        lmin = fminf(lmin, v);
        lmax = fmaxf(lmax, v);
    }
#pragma unroll
    for (int off = 32; off >= 1; off >>= 1) {
        lmin = fminf(lmin, __shfl_down(lmin, off));
        lmax = fmaxf(lmax, __shfl_down(lmax, off));
    }
    if ((threadIdx.x & 63) == 0) {
        atomicMin(&mmin[b], fkey(lmin));
        atomicMax(&mmax[b], fkey(lmax));
    }
}

__global__ __launch_bounds__(256) void norm_k(
    const float* __restrict__ img, const unsigned* __restrict__ mmin,
    const unsigned* __restrict__ mmax, float* __restrict__ out)
{
    int i = blockIdx.x * 256 + threadIdx.x;
    int b = i >> 16;
    float mn = funkey(mmin[b]), mx = funkey(mmax[b]);
    out[i] = (img[i] - mn) / (mx - mn);
}

// ---------- host ----------

static double i0_host(double x) {
    double sum = 1.0, term = 1.0;
    double q = x * x * 0.25;
    for (int k = 1; k < 80; ++k) {
        term *= q / ((double)k * (double)k);
        sum += term;
        if (term < sum * 1e-17) break;
    }
    return sum;
}

extern "C" void kernel_launch(void* const* d_in, const int* in_sizes, int n_in,
                              void* d_out, int out_size, void* d_ws, size_t ws_size,
                              hipStream_t stream)
{
    const float* y_real  = (const float*)d_in[0];
    const float* y_imag  = (const float*)d_in[1];
    const float* weights = (const float*)d_in[2];
    const float* uv      = (const float*)d_in[3];
    float* out = (float*)d_out;

    char* W = (char*)d_ws;
    // Aliased live ranges (peak 25.8 MB < 26.5 MB proven in round 2):
    //  phase bin:   counts/bsum/boff in [0,16M) (grid dead), frac/ytw/list/offsets in A
    //  phase gather: writes grid [0,16M); binning arrays live in A
    //  phase fft1:  reads grid, writes G = A+[0,8M) (binning arrays dead)
    //  phase fft2:  reads G, writes img [0,2M) (grid dead); mm at A+9.0M (dead tail)
    float*    grid    = (float*)W;                         // 16 MB
    int*      counts  = (int*)W;                           // 1 MB   (aliases grid)
    int*      bsum    = (int*)(W + 0x100000);              // 1 KB
    int*      boff    = (int*)(W + 0x100400);              // 1 KB
    char*     A       = W + (size_t)16 * 1024 * 1024;
    float2*   frac    = (float2*)(A);                      // 800,000 B
    float2*   ytw     = (float2*)(A + 800000);             // 6,400,000 B
    int*      list    = (int*)(A + 7200000);               // 400,000 B
    int*      offsets = (int*)(A + 7600000);               // 1,048,580 B
    float2*   G       = (float2*)A;                        // 8 MB (aliases binning)
    unsigned* mmin    = (unsigned*)(A + 9000000);          // 32 B
    unsigned* mmax    = (unsigned*)(A + 9000064);          // 32 B
    float*    img     = (float*)W;                         // 2 MB (aliases grid)

    double beta_d = M_PI * sqrt(19.45);   // BETA with alpha=2
    float beta = (float)beta_d;
    float inv_i0b = (float)(1.0 / i0_host(beta_d));
    float beta2 = (float)(beta_d * beta_d);

    hipMemsetAsync(counts, 0, NBINS * sizeof(int), stream);

    prep_points<<<(MPTS + 255) / 256, 256, 0, stream>>>(
        y_real, y_imag, weights, uv, frac, ytw, counts);

    scan1<<<256, 1024, 0, stream>>>(counts, offsets, bsum);
    scan2<<<1, 256, 0, stream>>>(bsum, boff);
    scan3<<<256, 1024, 0, stream>>>(offsets, boff);

    fill_bins<<<(MPTS + 255) / 256, 256, 0, stream>>>(uv, offsets, counts, list);

    gather_grid<<<NBINS / 256, 256, 0, stream>>>(
        offsets, list, frac, ytw, grid, beta, inv_i0b);

    fft1<<<512, 512, 0, stream>>>((const float2*)grid, G);

    fft2<<<512, 256, 0, stream>>>(G, img, beta2);

    hipMemsetAsync(mmin, 0xFF, 32, stream);
    hipMemsetAsync(mmax, 0x00, 32, stream);

    minmax2<<<256, 256, 0, stream>>>(img, mmin, mmax);

    norm_k<<<(BB * NN * NN) / 256, 256, 0, stream>>>(img, mmin, mmax, out);
}

// Round 5
// 191.052 us; speedup vs baseline: 17.3554x; 1.2804x over previous
//
#include <hip/hip_runtime.h>
#include <math.h>

// Problem constants
#define NN 256
#define KK 512
#define JJ 6
#define BB 8
#define MPTS 100000
#define NBINS (KK * KK)
// K/(2*pi)
#define KF_SCALE 81.48733086305615f

typedef _Float16 h8 __attribute__((ext_vector_type(8)));
typedef float v2f __attribute__((ext_vector_type(2)));

// ---------- device helpers ----------

// Abramowitz & Stegun 9.8.1 / 9.8.2 modified Bessel I0, float
__device__ __forceinline__ float i0f_dev(float x) {
    float ax = fabsf(x);
    if (ax < 3.75f) {
        float t = x / 3.75f; t *= t;
        return 1.0f + t*(3.5156229f + t*(3.0899424f + t*(1.2067492f +
               t*(0.2659732f + t*(0.0360768f + t*0.0045813f)))));
    } else {
        float t = 3.75f / ax;
        return (expf(ax) * rsqrtf(ax)) *
               (0.39894228f + t*(0.01328592f + t*(0.00225319f + t*(-0.00157565f +
                t*(0.00916281f + t*(-0.02057706f + t*(0.02635537f +
                t*(-0.01647633f + t*0.00392377f))))))));
    }
}

__device__ __forceinline__ float kbf(float t, float beta, float inv_i0b) {
    float u = t * (1.0f / 3.0f);       // 2*t/J, J=6
    float q = fmaxf(1.0f - u * u, 0.0f);
    return i0f_dev(beta * sqrtf(q)) * inv_i0b;
}

// order-preserving float<->uint for atomic min/max
__device__ __forceinline__ unsigned fkey(float f) {
    unsigned u = __float_as_uint(f);
    return (u & 0x80000000u) ? ~u : (u | 0x80000000u);
}
__device__ __forceinline__ float funkey(unsigned k) {
    unsigned u = (k & 0x80000000u) ? (k & 0x7FFFFFFFu) : ~k;
    return __uint_as_float(u);
}

// ---------- binning kernels ----------

__global__ __launch_bounds__(256) void count_bins(
    const float2* __restrict__ uv2, int* __restrict__ counts)
{
    int m = blockIdx.x * 256 + threadIdx.x;
    if (m >= MPTS) return;
    float2 u = uv2[m];
    int b0 = (int)floorf(u.x * KF_SCALE) & (KK - 1);
    int b1 = (int)floorf(u.y * KF_SCALE) & (KK - 1);
    atomicAdd(&counts[(b0 << 9) | b1], 1);
}

__global__ __launch_bounds__(1024) void scan1(
    const int* __restrict__ counts, int* __restrict__ offsets, int* __restrict__ bsum)
{
    __shared__ int s[1024];
    int i = blockIdx.x * 1024 + threadIdx.x;
    int v = counts[i];
    s[threadIdx.x] = v;
    for (int off = 1; off < 1024; off <<= 1) {
        __syncthreads();
        int t = (threadIdx.x >= off) ? s[threadIdx.x - off] : 0;
        __syncthreads();
        s[threadIdx.x] += t;
    }
    offsets[i] = s[threadIdx.x] - v;
    if (threadIdx.x == 1023) bsum[blockIdx.x] = s[1023];
}

// scan2 also initializes the min/max atomic cells (runs well before fft2).
__global__ __launch_bounds__(256) void scan2(
    const int* __restrict__ bsum, int* __restrict__ boff,
    unsigned* __restrict__ mmin, unsigned* __restrict__ mmax)
{
    __shared__ int s[256];
    int v = bsum[threadIdx.x];
    s[threadIdx.x] = v;
    if (threadIdx.x < 8)  mmin[threadIdx.x] = 0xFFFFFFFFu;
    else if (threadIdx.x < 16) mmax[threadIdx.x - 8] = 0u;
    for (int off = 1; off < 256; off <<= 1) {
        __syncthreads();
        int t = (threadIdx.x >= off) ? s[threadIdx.x - off] : 0;
        __syncthreads();
        s[threadIdx.x] += t;
    }
    boff[threadIdx.x] = s[threadIdx.x] - v;
}

__global__ __launch_bounds__(1024) void scan3(
    int* __restrict__ offsets, const int* __restrict__ boff)
{
    int i = blockIdx.x * 1024 + threadIdx.x;
    offsets[i] += boff[blockIdx.x];
    if (i == 0) offsets[NBINS] = MPTS;
}

// fill_records: compute 12 KB weights (f16) + pre-weighted y (f16, 8 batches)
// and write the point's record directly to its CSR slot (sorted by bin).
__global__ __launch_bounds__(256) void fill_records(
    const float2* __restrict__ uv2,
    const float* __restrict__ y_real, const float* __restrict__ y_imag,
    const float* __restrict__ weights, const int* __restrict__ offsets,
    int* __restrict__ counts, _Float16* __restrict__ warr,
    _Float16* __restrict__ yarr, float beta, float inv_i0b)
{
    int m = blockIdx.x * 256 + threadIdx.x;
    if (m >= MPTS) return;
    float2 u = uv2[m];
    float kf0 = u.x * KF_SCALE;
    float kf1 = u.y * KF_SCALE;
    float f0 = floorf(kf0), f1 = floorf(kf1);
    float fr0 = kf0 - f0, fr1 = kf1 - f1;
    int bin = (((int)f0 & (KK - 1)) << 9) | ((int)f1 & (KK - 1));
    int old = atomicSub(&counts[bin], 1);
    int slot = offsets[bin] + old - 1;

    _Float16* w = warr + slot * 12;
#pragma unroll
    for (int j = 0; j < JJ; ++j) {
        w[j]     = (_Float16)kbf((float)(j - 2) - fr0, beta, inv_i0b);
        w[6 + j] = (_Float16)kbf((float)(j - 2) - fr1, beta, inv_i0b);
    }

    float wm = weights[m];
    h8 ha, hb;
#pragma unroll
    for (int b = 0; b < 4; ++b) {
        ha[2 * b]     = (_Float16)(y_real[b * MPTS + m] * wm);
        ha[2 * b + 1] = (_Float16)(y_imag[b * MPTS + m] * wm);
        hb[2 * b]     = (_Float16)(y_real[(b + 4) * MPTS + m] * wm);
        hb[2 * b + 1] = (_Float16)(y_imag[(b + 4) * MPTS + m] * wm);
    }
    h8* yv = (h8*)yarr;
    yv[slot * 2]     = ha;
    yv[slot * 2 + 1] = hb;
}

// ---------- gather v3: sorted records, precomputed f16 weights ----------

__global__ __launch_bounds__(256) void gather_grid(
    const int* __restrict__ offsets, const _Float16* __restrict__ warr,
    const _Float16* __restrict__ yarr, float* __restrict__ grid)
{
    int c = blockIdx.x * 256 + threadIdx.x;
    int c0 = c >> 9, c1 = c & (KK - 1);

    float aR[BB], aI[BB];
#pragma unroll
    for (int b = 0; b < BB; ++b) { aR[b] = 0.0f; aI[b] = 0.0f; }

    bool fast = (c1 >= 3) && (c1 <= 509);
    const h8* yv = (const h8*)yarr;

    for (int j0 = 0; j0 < JJ; ++j0) {
        int rb = ((c0 - (j0 - 2)) & (KK - 1)) << 9;
        if (fast) {
            int base = rb + c1 - 3;
            int e0 = offsets[base];
            int e1 = offsets[base + 1];
            int e2 = offsets[base + 2];
            int e3 = offsets[base + 3];
            int e4 = offsets[base + 4];
            int e5 = offsets[base + 5];
            int e6 = offsets[base + 6];
            for (int p = e0; p < e6; ++p) {
                int jc = (p >= e1) + (p >= e2) + (p >= e3) + (p >= e4) + (p >= e5);
                float w0f = (float)warr[p * 12 + j0];
                float w1f = (float)warr[p * 12 + 11 - jc];
                float ww = w0f * w1f;
                h8 ya = yv[p * 2];
                h8 yb = yv[p * 2 + 1];
#pragma unroll
                for (int b = 0; b < 4; ++b) {
                    aR[b]     += (float)ya[2 * b]     * ww;   // v_fma_mix
                    aI[b]     += (float)ya[2 * b + 1] * ww;
                    aR[b + 4] += (float)yb[2 * b]     * ww;
                    aI[b + 4] += (float)yb[2 * b + 1] * ww;
                }
            }
        } else {
            for (int j1 = 0; j1 < JJ; ++j1) {
                int bin = rb | ((c1 - (j1 - 2)) & (KK - 1));
                int s = offsets[bin];
                int e = offsets[bin + 1];
                for (int p = s; p < e; ++p) {
                    float w0f = (float)warr[p * 12 + j0];
                    float w1f = (float)warr[p * 12 + 6 + j1];
                    float ww = w0f * w1f;
                    h8 ya = yv[p * 2];
                    h8 yb = yv[p * 2 + 1];
#pragma unroll
                    for (int b = 0; b < 4; ++b) {
                        aR[b]     += (float)ya[2 * b]     * ww;
                        aI[b]     += (float)ya[2 * b + 1] * ww;
                        aR[b + 4] += (float)yb[2 * b]     * ww;
                        aI[b + 4] += (float)yb[2 * b + 1] * ww;
                    }
                }
            }
        }
    }

    float2* g2 = (float2*)grid;
#pragma unroll
    for (int b = 0; b < BB; ++b)
        g2[((size_t)b << 18) + c] = make_float2(aR[b], aI[b]);
}

// ---------- FFT kernels (radix-2 DIT in LDS, +i sign = inverse transform) ----------

// fft1: 512-pt FFT over k1 for 8 k2-columns per block. 512 blocks (b = blk&7),
// 512 threads. Output: G[b][r][k2] = X[(384+r)&511], r in [0,256).
__global__ __launch_bounds__(512) void fft1(
    const float2* __restrict__ grid2, float2* __restrict__ Gout)
{
    __shared__ float2 data[KK][9];    // [idx][col], pad 9 breaks bank conflicts
    __shared__ float2 tw[256];
    int b = blockIdx.x & 7;
    int k2base = (blockIdx.x >> 3) << 3;
    int t = threadIdx.x;
    int col = t & 7;
    int u = t >> 3;                   // [0,64)

    if (t < 256) {
        float ang = (float)(2.0 * M_PI / 512.0) * (float)t;
        float s, c; sincosf(ang, &s, &c);
        tw[t] = make_float2(c, s);
    }

    const float2* gb = grid2 + (size_t)b * (KK * KK);
#pragma unroll
    for (int pass = 0; pass < 8; ++pass) {
        int k1 = (pass << 6) + u;
        float2 v = gb[k1 * KK + k2base + col];
        data[__brev((unsigned)k1) >> 23][col] = v;
    }
    __syncthreads();

#pragma unroll
    for (int s = 0; s < 9; ++s) {
        int half = 1 << s;
#pragma unroll
        for (int q = 0; q < 4; ++q) {
            int i = (q << 6) + u;                       // [0,256)
            int j = i & (half - 1);
            int idx1 = ((i >> s) << (s + 1)) + j;
            int idx2 = idx1 + half;
            float2 w = tw[j << (8 - s)];
            float2 d1 = data[idx1][col];
            float2 d2 = data[idx2][col];
            float2 tt = make_float2(w.x * d2.x - w.y * d2.y,
                                    w.x * d2.y + w.y * d2.x);
            data[idx1][col] = make_float2(d1.x + tt.x, d1.y + tt.y);
            data[idx2][col] = make_float2(d1.x - tt.x, d1.y - tt.y);
        }
        __syncthreads();
    }

#pragma unroll
    for (int pass = 0; pass < 4; ++pass) {
        int r = (pass << 6) + u;
        int x = (384 + r) & (KK - 1);
        Gout[((size_t)(b << 8) + r) * KK + k2base + col] = data[x][col];
    }
}

// fft2: 512-pt FFT over k2 for 4 (b,r)-rows per block + apod epilogue + fused
// per-batch min/max atomics. 512 blocks, 256 threads.
__global__ __launch_bounds__(256) void fft2(
    const float2* __restrict__ G, float* __restrict__ img, float beta2,
    unsigned* __restrict__ mmin, unsigned* __restrict__ mmax)
{
    __shared__ float2 data[KK][5];    // [idx][row], pad 5
    __shared__ float2 tw[256];
    int t = threadIdx.x;
    int rowbase = blockIdx.x << 2;    // global row = b*256 + r
    int lrow = t >> 6;                // [0,4): one wave per row
    int lk = t & 63;
    int col = t & 3;                  // butterfly-phase row
    int u = t >> 2;                   // [0,64)

    if (t < 256) {
        float ang = (float)(2.0 * M_PI / 512.0) * (float)t;
        float s, c; sincosf(ang, &s, &c);
        tw[t] = make_float2(c, s);
    }

    const float2* Grow = G + (size_t)(rowbase + lrow) * KK;
#pragma unroll
    for (int pass = 0; pass < 8; ++pass) {
        int k2 = (pass << 6) + lk;
        data[__brev((unsigned)k2) >> 23][lrow] = Grow[k2];
    }
    __syncthreads();

#pragma unroll
    for (int s = 0; s < 9; ++s) {
        int half = 1 << s;
#pragma unroll
        for (int q = 0; q < 4; ++q) {
            int i = (q << 6) + u;
            int j = i & (half - 1);
            int idx1 = ((i >> s) << (s + 1)) + j;
            int idx2 = idx1 + half;
            float2 w = tw[j << (8 - s)];
            float2 d1 = data[idx1][col];
            float2 d2 = data[idx2][col];
            float2 tt = make_float2(w.x * d2.x - w.y * d2.y,
                                    w.x * d2.y + w.y * d2.x);
            data[idx1][col] = make_float2(d1.x + tt.x, d1.y + tt.y);
            data[idx2][col] = make_float2(d1.x - tt.x, d1.y - tt.y);
        }
        __syncthreads();
    }

    int grow = rowbase + lrow;
    int b = grow >> 8;
    int r = grow & (NN - 1);
    const float XF = (float)(M_PI * (double)JJ / (double)KK);
    float nr = (float)(r - 128);
    float xfr = XF * nr;
    float arq = beta2 - xfr * xfr;
    float srq = sqrtf(arq);
    float dr = sinhf(srq) / srq;

    float lmin = 1e30f, lmax = -1e30f;
#pragma unroll
    for (int pass = 0; pass < 4; ++pass) {
        int s2 = (pass << 6) + lk;
        int x = (384 + s2) & (KK - 1);
        float val = data[x][lrow].x;
        float ns = (float)(s2 - 128);
        float xfs = XF * ns;
        float asq = beta2 - xfs * xfs;
        float ssq = sqrtf(asq);
        float ds = sinhf(ssq) / ssq;
        float o = val * (1.0f / ((float)KK * (float)KK)) / (dr * ds);
        img[(size_t)grow * NN + s2] = o;
        lmin = fminf(lmin, o);
        lmax = fmaxf(lmax, o);
    }
#pragma unroll
    for (int off = 32; off >= 1; off >>= 1) {
        lmin = fminf(lmin, __shfl_down(lmin, off));
        lmax = fmaxf(lmax, __shfl_down(lmax, off));
    }
    if ((t & 63) == 0) {
        atomicMin(&mmin[b], fkey(lmin));
        atomicMax(&mmax[b], fkey(lmax));
    }
}

__global__ __launch_bounds__(256) void norm_k(
    const float* __restrict__ img, const unsigned* __restrict__ mmin,
    const unsigned* __restrict__ mmax, float* __restrict__ out)
{
    int i = blockIdx.x * 256 + threadIdx.x;
    int b = i >> 16;
    float mn = funkey(mmin[b]), mx = funkey(mmax[b]);
    out[i] = (img[i] - mn) / (mx - mn);
}

// ---------- host ----------

static double i0_host(double x) {
    double sum = 1.0, term = 1.0;
    double q = x * x * 0.25;
    for (int k = 1; k < 80; ++k) {
        term *= q / ((double)k * (double)k);
        sum += term;
        if (term < sum * 1e-17) break;
    }
    return sum;
}

extern "C" void kernel_launch(void* const* d_in, const int* in_sizes, int n_in,
                              void* d_out, int out_size, void* d_ws, size_t ws_size,
                              hipStream_t stream)
{
    const float* y_real  = (const float*)d_in[0];
    const float* y_imag  = (const float*)d_in[1];
    const float* weights = (const float*)d_in[2];
    const float* uv      = (const float*)d_in[3];
    float* out = (float*)d_out;

    char* W = (char*)d_ws;
    // Aliased live ranges (peak 25.18 MB, under the 26.4 MB proven in round 2):
    //  W[0,16M): counts/bsum/boff (pre-gather) -> grid (gather->fft1) -> img [0,2M)
    //  A=W+16M:  warr [0,2.4M) + yarr [2.4M,5.6M) + offsets [5.6M,6.65M) (bin->gather)
    //            -> G [0,8.39M) (fft1->fft2);  mm at [8.4M,8.4M+96) (scan2->norm)
    float*    grid    = (float*)W;                         // 16 MB
    int*      counts  = (int*)W;                           // 1 MB (aliases grid)
    int*      bsum    = (int*)(W + 0x100000);
    int*      boff    = (int*)(W + 0x100400);
    float*    img     = (float*)W;                         // 2 MB (aliases grid)
    char*     A       = W + (size_t)16 * 1024 * 1024;
    _Float16* warr    = (_Float16*)A;                      // 2,400,000 B
    _Float16* yarr    = (_Float16*)(A + 2400000);          // 3,200,000 B
    int*      offsets = (int*)(A + 5600000);               // 1,048,580 B
    float2*   G       = (float2*)A;                        // 8 MB (aliases binning)
    unsigned* mmin    = (unsigned*)(A + 8400000);          // 32 B
    unsigned* mmax    = (unsigned*)(A + 8400064);          // 32 B

    double beta_d = M_PI * sqrt(19.45);   // BETA with alpha=2
    float beta = (float)beta_d;
    float inv_i0b = (float)(1.0 / i0_host(beta_d));
    float beta2 = (float)(beta_d * beta_d);

    hipMemsetAsync(counts, 0, NBINS * sizeof(int), stream);

    count_bins<<<(MPTS + 255) / 256, 256, 0, stream>>>((const float2*)uv, counts);

    scan1<<<256, 1024, 0, stream>>>(counts, offsets, bsum);
    scan2<<<1, 256, 0, stream>>>(bsum, boff, mmin, mmax);
    scan3<<<256, 1024, 0, stream>>>(offsets, boff);

    fill_records<<<(MPTS + 255) / 256, 256, 0, stream>>>(
        (const float2*)uv, y_real, y_imag, weights, offsets, counts,
        warr, yarr, beta, inv_i0b);

    gather_grid<<<NBINS / 256, 256, 0, stream>>>(offsets, warr, yarr, grid);

    fft1<<<512, 512, 0, stream>>>((const float2*)grid, G);

    fft2<<<512, 256, 0, stream>>>(G, img, beta2, mmin, mmax);

    norm_k<<<(BB * NN * NN) / 256, 256, 0, stream>>>(img, mmin, mmax, out);
}

// Round 6
// 183.877 us; speedup vs baseline: 18.0326x; 1.0390x over previous
//
#include <hip/hip_runtime.h>
#include <math.h>

// Problem constants
#define NN 256
#define KK 512
#define JJ 6
#define BB 8
#define MPTS 100000
#define NBINS (KK * KK)
// K/(2*pi)
#define KF_SCALE 81.48733086305615f

typedef _Float16 h8 __attribute__((ext_vector_type(8)));

// ---------- device helpers ----------

// Abramowitz & Stegun 9.8.1 / 9.8.2 modified Bessel I0, float
__device__ __forceinline__ float i0f_dev(float x) {
    float ax = fabsf(x);
    if (ax < 3.75f) {
        float t = x / 3.75f; t *= t;
        return 1.0f + t*(3.5156229f + t*(3.0899424f + t*(1.2067492f +
               t*(0.2659732f + t*(0.0360768f + t*0.0045813f)))));
    } else {
        float t = 3.75f / ax;
        return (expf(ax) * rsqrtf(ax)) *
               (0.39894228f + t*(0.01328592f + t*(0.00225319f + t*(-0.00157565f +
                t*(0.00916281f + t*(-0.02057706f + t*(0.02635537f +
                t*(-0.01647633f + t*0.00392377f))))))));
    }
}

__device__ __forceinline__ float kbf(float t, float beta, float inv_i0b) {
    float u = t * (1.0f / 3.0f);       // 2*t/J, J=6
    float q = fmaxf(1.0f - u * u, 0.0f);
    return i0f_dev(beta * sqrtf(q)) * inv_i0b;
}

// order-preserving float<->uint for atomic min/max
__device__ __forceinline__ unsigned fkey(float f) {
    unsigned u = __float_as_uint(f);
    return (u & 0x80000000u) ? ~u : (u | 0x80000000u);
}
__device__ __forceinline__ float funkey(unsigned k) {
    unsigned u = (k & 0x80000000u) ? (k & 0x7FFFFFFFu) : ~k;
    return __uint_as_float(u);
}

// ---------- binning kernels ----------

__global__ __launch_bounds__(256) void count_bins(
    const float2* __restrict__ uv2, int* __restrict__ counts)
{
    int m = blockIdx.x * 256 + threadIdx.x;
    if (m >= MPTS) return;
    float2 u = uv2[m];
    int b0 = (int)floorf(u.x * KF_SCALE) & (KK - 1);
    int b1 = (int)floorf(u.y * KF_SCALE) & (KK - 1);
    atomicAdd(&counts[(b0 << 9) | b1], 1);
}

__global__ __launch_bounds__(1024) void scan1(
    const int* __restrict__ counts, int* __restrict__ offsets, int* __restrict__ bsum)
{
    __shared__ int s[1024];
    int i = blockIdx.x * 1024 + threadIdx.x;
    int v = counts[i];
    s[threadIdx.x] = v;
    for (int off = 1; off < 1024; off <<= 1) {
        __syncthreads();
        int t = (threadIdx.x >= off) ? s[threadIdx.x - off] : 0;
        __syncthreads();
        s[threadIdx.x] += t;
    }
    offsets[i] = s[threadIdx.x] - v;
    if (threadIdx.x == 1023) bsum[blockIdx.x] = s[1023];
}

// scan2 also initializes the min/max atomic cells (runs well before fftB).
__global__ __launch_bounds__(256) void scan2(
    const int* __restrict__ bsum, int* __restrict__ boff,
    unsigned* __restrict__ mmin, unsigned* __restrict__ mmax)
{
    __shared__ int s[256];
    int v = bsum[threadIdx.x];
    s[threadIdx.x] = v;
    if (threadIdx.x < 8)  mmin[threadIdx.x] = 0xFFFFFFFFu;
    else if (threadIdx.x < 16) mmax[threadIdx.x - 8] = 0u;
    for (int off = 1; off < 256; off <<= 1) {
        __syncthreads();
        int t = (threadIdx.x >= off) ? s[threadIdx.x - off] : 0;
        __syncthreads();
        s[threadIdx.x] += t;
    }
    boff[threadIdx.x] = s[threadIdx.x] - v;
}

__global__ __launch_bounds__(1024) void scan3(
    int* __restrict__ offsets, const int* __restrict__ boff)
{
    int i = blockIdx.x * 1024 + threadIdx.x;
    offsets[i] += boff[blockIdx.x];
    if (i == 0) offsets[NBINS] = MPTS;
}

// fill_records: compute 12 KB weights (f16) + pre-weighted y (f16, 8 batches)
// and write the point's record directly to its CSR slot (sorted by bin).
__global__ __launch_bounds__(256) void fill_records(
    const float2* __restrict__ uv2,
    const float* __restrict__ y_real, const float* __restrict__ y_imag,
    const float* __restrict__ weights, const int* __restrict__ offsets,
    int* __restrict__ counts, _Float16* __restrict__ warr,
    _Float16* __restrict__ yarr, float beta, float inv_i0b)
{
    int m = blockIdx.x * 256 + threadIdx.x;
    if (m >= MPTS) return;
    float2 u = uv2[m];
    float kf0 = u.x * KF_SCALE;
    float kf1 = u.y * KF_SCALE;
    float f0 = floorf(kf0), f1 = floorf(kf1);
    float fr0 = kf0 - f0, fr1 = kf1 - f1;
    int bin = (((int)f0 & (KK - 1)) << 9) | ((int)f1 & (KK - 1));
    int old = atomicSub(&counts[bin], 1);
    int slot = offsets[bin] + old - 1;

    _Float16* w = warr + slot * 12;
#pragma unroll
    for (int j = 0; j < JJ; ++j) {
        w[j]     = (_Float16)kbf((float)(j - 2) - fr0, beta, inv_i0b);
        w[6 + j] = (_Float16)kbf((float)(j - 2) - fr1, beta, inv_i0b);
    }

    float wm = weights[m];
    h8 ha, hb;
#pragma unroll
    for (int b = 0; b < 4; ++b) {
        ha[2 * b]     = (_Float16)(y_real[b * MPTS + m] * wm);
        ha[2 * b + 1] = (_Float16)(y_imag[b * MPTS + m] * wm);
        hb[2 * b]     = (_Float16)(y_real[(b + 4) * MPTS + m] * wm);
        hb[2 * b + 1] = (_Float16)(y_imag[(b + 4) * MPTS + m] * wm);
    }
    h8* yv = (h8*)yarr;
    yv[slot * 2]     = ha;
    yv[slot * 2 + 1] = hb;
}

// ---------- gather v3: sorted records, precomputed f16 weights ----------

__global__ __launch_bounds__(256) void gather_grid(
    const int* __restrict__ offsets, const _Float16* __restrict__ warr,
    const _Float16* __restrict__ yarr, float* __restrict__ grid)
{
    int c = blockIdx.x * 256 + threadIdx.x;
    int c0 = c >> 9, c1 = c & (KK - 1);

    float aR[BB], aI[BB];
#pragma unroll
    for (int b = 0; b < BB; ++b) { aR[b] = 0.0f; aI[b] = 0.0f; }

    bool fast = (c1 >= 3) && (c1 <= 509);
    const h8* yv = (const h8*)yarr;

    for (int j0 = 0; j0 < JJ; ++j0) {
        int rb = ((c0 - (j0 - 2)) & (KK - 1)) << 9;
        if (fast) {
            int base = rb + c1 - 3;
            int e0 = offsets[base];
            int e1 = offsets[base + 1];
            int e2 = offsets[base + 2];
            int e3 = offsets[base + 3];
            int e4 = offsets[base + 4];
            int e5 = offsets[base + 5];
            int e6 = offsets[base + 6];
            for (int p = e0; p < e6; ++p) {
                int jc = (p >= e1) + (p >= e2) + (p >= e3) + (p >= e4) + (p >= e5);
                float w0f = (float)warr[p * 12 + j0];
                float w1f = (float)warr[p * 12 + 11 - jc];
                float ww = w0f * w1f;
                h8 ya = yv[p * 2];
                h8 yb = yv[p * 2 + 1];
#pragma unroll
                for (int b = 0; b < 4; ++b) {
                    aR[b]     += (float)ya[2 * b]     * ww;   // v_fma_mix
                    aI[b]     += (float)ya[2 * b + 1] * ww;
                    aR[b + 4] += (float)yb[2 * b]     * ww;
                    aI[b + 4] += (float)yb[2 * b + 1] * ww;
                }
            }
        } else {
            for (int j1 = 0; j1 < JJ; ++j1) {
                int bin = rb | ((c1 - (j1 - 2)) & (KK - 1));
                int s = offsets[bin];
                int e = offsets[bin + 1];
                for (int p = s; p < e; ++p) {
                    float w0f = (float)warr[p * 12 + j0];
                    float w1f = (float)warr[p * 12 + 6 + j1];
                    float ww = w0f * w1f;
                    h8 ya = yv[p * 2];
                    h8 yb = yv[p * 2 + 1];
#pragma unroll
                    for (int b = 0; b < 4; ++b) {
                        aR[b]     += (float)ya[2 * b]     * ww;
                        aI[b]     += (float)ya[2 * b + 1] * ww;
                        aR[b + 4] += (float)yb[2 * b]     * ww;
                        aI[b + 4] += (float)yb[2 * b + 1] * ww;
                    }
                }
            }
        }
    }

    float2* g2 = (float2*)grid;
#pragma unroll
    for (int b = 0; b < BB; ++b)
        g2[((size_t)b << 18) + c] = make_float2(aR[b], aI[b]);
}

// ---------- per-wave 512-pt FFT: 8(reg) x 64(lanes via shfl), sign +i ----------
// Input:  lane holds x[brev6(lane) + 64a] in (xr[a], xi[a]).
// Output: lane holds X[d + 8*lane] in (xr[d], xi[d]),
//         X[k] = sum_n x[n] e^{+2*pi*i*n*k/512}.
__device__ __forceinline__ void wave_fft512(float xr[8], float xi[8], int lane)
{
    // ---- in-register FFT8 over a (natural in / natural out, +i) ----
    float a0r = xr[0]+xr[4], a0i = xi[0]+xi[4];
    float a4r = xr[0]-xr[4], a4i = xi[0]-xi[4];
    float a2r = xr[2]+xr[6], a2i = xi[2]+xi[6];
    float a6r = xr[2]-xr[6], a6i = xi[2]-xi[6];
    float a1r = xr[1]+xr[5], a1i = xi[1]+xi[5];
    float a5r = xr[1]-xr[5], a5i = xi[1]-xi[5];
    float a3r = xr[3]+xr[7], a3i = xi[3]+xi[7];
    float a7r = xr[3]-xr[7], a7i = xi[3]-xi[7];
    float b0r = a0r+a2r, b0i = a0i+a2i;
    float b2r = a0r-a2r, b2i = a0i-a2i;
    float b4r = a4r-a6i, b4i = a4i+a6r;    // a4 + i*a6
    float b6r = a4r+a6i, b6i = a4i-a6r;    // a4 - i*a6
    float b1r = a1r+a3r, b1i = a1i+a3i;
    float b3r = a1r-a3r, b3i = a1i-a3i;
    float b5r = a5r-a7i, b5i = a5i+a7r;
    float b7r = a5r+a7i, b7i = a5i-a7r;
    const float S2 = 0.70710678118654752f;
    float w5r = S2*(b5r-b5i), w5i = S2*(b5r+b5i);     // W8^1 * b5, W8 = (S2+i*S2)
    float w7r = -S2*(b7r+b7i), w7i = S2*(b7r-b7i);    // W8^3 * b7, W8^3 = (-S2+i*S2)
    float y0r = b0r+b1r, y0i = b0i+b1i;
    float y4r = b0r-b1r, y4i = b0i-b1i;
    float y1r = b4r+w5r, y1i = b4i+w5i;
    float y5r = b4r-w5r, y5i = b4i-w5i;
    float y2r = b2r-b3i, y2i = b2i+b3r;    // b2 + i*b3
    float y6r = b2r+b3i, y6i = b2i-b3r;
    float y3r = b6r+w7r, y3i = b6i+w7i;
    float y7r = b6r-w7r, y7i = b6i-w7i;

    // ---- twiddle T[d] = Y[d] * w^(p*d), w = e^{+2pi i p/512}, p = brev6(lane) ----
    int p = __brev((unsigned)lane) >> 26;
    float ang = (float)(2.0 * M_PI / 512.0) * (float)p;
    float c1, s1; sincosf(ang, &s1, &c1);
    float wr = c1, wi = s1, tr;
    xr[0] = y0r; xi[0] = y0i;
    xr[1] = y1r*wr - y1i*wi; xi[1] = y1i*wr + y1r*wi;
    tr = wr*c1 - wi*s1; wi = wr*s1 + wi*c1; wr = tr;
    xr[2] = y2r*wr - y2i*wi; xi[2] = y2i*wr + y2r*wi;
    tr = wr*c1 - wi*s1; wi = wr*s1 + wi*c1; wr = tr;
    xr[3] = y3r*wr - y3i*wi; xi[3] = y3i*wr + y3r*wi;
    tr = wr*c1 - wi*s1; wi = wr*s1 + wi*c1; wr = tr;
    xr[4] = y4r*wr - y4i*wi; xi[4] = y4i*wr + y4r*wi;
    tr = wr*c1 - wi*s1; wi = wr*s1 + wi*c1; wr = tr;
    xr[5] = y5r*wr - y5i*wi; xi[5] = y5i*wr + y5r*wi;
    tr = wr*c1 - wi*s1; wi = wr*s1 + wi*c1; wr = tr;
    xr[6] = y6r*wr - y6i*wi; xi[6] = y6i*wr + y6r*wi;
    tr = wr*c1 - wi*s1; wi = wr*s1 + wi*c1; wr = tr;
    xr[7] = y7r*wr - y7i*wi; xi[7] = y7i*wr + y7r*wi;

    // ---- cross-lane FFT64 over p (DIT, bit-reversed input order in lanes) ----
#pragma unroll
    for (int t = 0; t < 6; ++t) {
        int m = 1 << t;
        int j = lane & (m - 1);
        float wc, wsn;
        sincosf((float)M_PI * (float)j / (float)m, &wsn, &wc);  // e^{+2pi i j/(2m)}
        bool hi = (lane & m) != 0;
#pragma unroll
        for (int d = 0; d < 8; ++d) {
            float pR = __shfl_xor(xr[d], m, 64);
            float pI = __shfl_xor(xi[d], m, 64);
            float bR = hi ? xr[d] : pR;
            float bI = hi ? xi[d] : pI;
            float aR = hi ? pR : xr[d];
            float aI = hi ? pI : xi[d];
            float wbR = wc * bR - wsn * bI;
            float wbI = wc * bI + wsn * bR;
            xr[d] = hi ? aR - wbR : aR + wbR;
            xi[d] = hi ? aI - wbI : aI + wbI;
        }
    }
}

// fftA: k2-transform. 512 blocks x 8 waves; wave = row (b, k1).
// Keeps the 256 fftshift-cropped outputs, transposes via swizzled LDS,
// stores C[b][s2][k1] with 64B-coalesced segments.
__global__ __launch_bounds__(512) void fftA(
    const float2* __restrict__ grid2, float2* __restrict__ C)
{
    __shared__ float sR[2112], sI[2112];   // 8 waves * 264, stride33 swizzle
    int t = threadIdx.x;
    int lane = t & 63;
    int w = t >> 6;
    int b = blockIdx.x & 7;
    int k1base = (blockIdx.x >> 3) << 3;
    int k1 = k1base + w;

    const float2* row = grid2 + ((size_t)b << 18) + ((size_t)k1 << 9);
    int p = __brev((unsigned)lane) >> 26;
    float xr[8], xi[8];
#pragma unroll
    for (int a = 0; a < 8; ++a) {
        float2 v = row[p + (a << 6)];
        xr[a] = v.x; xi[a] = v.y;
    }

    wave_fft512(xr, xi, lane);

    // keep k = d+8*lane in [0,128)U[384,512): lanes <16 or >=48
    bool act = (lane < 16) | (lane >= 48);
    int lpp = (lane < 16) ? lane : (lane - 32);   // [0,32)
    if (act) {
#pragma unroll
        for (int d = 0; d < 8; ++d) {
            int addr = w * 264 + d * 33 + lpp;    // banks (8w+d+lpp)%32: conflict-free
            sR[addr] = xr[d];
            sI[addr] = xi[d];
        }
    }
    __syncthreads();

#pragma unroll
    for (int pp = 0; pp < 4; ++pp) {
        int idx = pp * 512 + t;                   // [0,2048) = 256 s2 x 8 k1
        int kk = idx & 7;
        int s2 = idx >> 3;
        int v = (s2 + 128) & 255;                 // v = 8*lpp + d
        int d = v & 7;
        int lp = v >> 3;
        int addr = kk * 264 + d * 33 + lp;
        C[(((size_t)(b << 8) + s2) << 9) + k1base + kk] = make_float2(sR[addr], sI[addr]);
    }
}

// fftB: k1-transform + apod + fused min/max. 512 blocks x 4 waves;
// wave = row (b, s2). No LDS, no barriers.
__global__ __launch_bounds__(256) void fftB(
    const float2* __restrict__ C, float* __restrict__ img, float beta2,
    unsigned* __restrict__ mmin, unsigned* __restrict__ mmax)
{
    int t = threadIdx.x;
    int lane = t & 63;
    int w = t >> 6;
    int rowid = blockIdx.x * 4 + w;               // [0,2048) = b*256 + s2
    int b = rowid >> 8;
    int s2 = rowid & 255;

    const float2* row = C + ((size_t)rowid << 9);
    int p = __brev((unsigned)lane) >> 26;
    float xr[8], xi[8];
#pragma unroll
    for (int a = 0; a < 8; ++a) {
        float2 v = row[p + (a << 6)];
        xr[a] = v.x; xi[a] = v.y;
    }

    wave_fft512(xr, xi, lane);

    const float XF = (float)(M_PI * (double)JJ / (double)KK);
    const float INVK2 = 1.0f / ((float)KK * (float)KK);
    float ns = (float)(s2 - 128);
    float xfs = XF * ns;
    float asq = beta2 - xfs * xfs;
    float ssq = sqrtf(asq);
    float ds = sinhf(ssq) / ssq;                  // wave-uniform
    float sbase = INVK2 / ds;

    bool act = (lane < 16) | (lane >= 48);
    int lpp = (lane < 16) ? lane : (lane - 32);
    float lmin = 1e30f, lmax = -1e30f;
    if (act) {
#pragma unroll
        for (int d = 0; d < 8; ++d) {
            int r = (8 * lpp + d + 128) & 255;
            float nr = (float)(r - 128);
            float xfr = XF * nr;
            float arq = beta2 - xfr * xfr;
            float srq = sqrtf(arq);
            float dr = sinhf(srq) / srq;
            float o = xr[d] * sbase / dr;
            img[((size_t)b << 16) + (r << 8) + s2] = o;
            lmin = fminf(lmin, o);
            lmax = fmaxf(lmax, o);
        }
    }
#pragma unroll
    for (int off = 32; off >= 1; off >>= 1) {
        lmin = fminf(lmin, __shfl_xor(lmin, off, 64));
        lmax = fmaxf(lmax, __shfl_xor(lmax, off, 64));
    }
    if (lane == 0) {
        atomicMin(&mmin[b], fkey(lmin));
        atomicMax(&mmax[b], fkey(lmax));
    }
}

__global__ __launch_bounds__(256) void norm_k(
    const float* __restrict__ img, const unsigned* __restrict__ mmin,
    const unsigned* __restrict__ mmax, float* __restrict__ out)
{
    int i = blockIdx.x * 256 + threadIdx.x;
    int b = i >> 16;
    float mn = funkey(mmin[b]), mx = funkey(mmax[b]);
    out[i] = (img[i] - mn) / (mx - mn);
}

// ---------- host ----------

static double i0_host(double x) {
    double sum = 1.0, term = 1.0;
    double q = x * x * 0.25;
    for (int k = 1; k < 80; ++k) {
        term *= q / ((double)k * (double)k);
        sum += term;
        if (term < sum * 1e-17) break;
    }
    return sum;
}

extern "C" void kernel_launch(void* const* d_in, const int* in_sizes, int n_in,
                              void* d_out, int out_size, void* d_ws, size_t ws_size,
                              hipStream_t stream)
{
    const float* y_real  = (const float*)d_in[0];
    const float* y_imag  = (const float*)d_in[1];
    const float* weights = (const float*)d_in[2];
    const float* uv      = (const float*)d_in[3];
    float* out = (float*)d_out;

    char* W = (char*)d_ws;
    // Aliased live ranges (peak 24.4 MB):
    //  W[0,16M): counts/bsum/boff (pre-gather) -> grid (gather->fftA) -> img [0,2M)
    //  A=W+16M:  warr/yarr/offsets (bin->gather) -> C [0,8M) (fftA->fftB)
    //            mm at [8.4M, 8.4M+96) (scan2 -> norm)
    float*    grid    = (float*)W;                         // 16 MB
    int*      counts  = (int*)W;                           // 1 MB (aliases grid)
    int*      bsum    = (int*)(W + 0x100000);
    int*      boff    = (int*)(W + 0x100400);
    float*    img     = (float*)W;                         // 2 MB (aliases grid)
    char*     A       = W + (size_t)16 * 1024 * 1024;
    _Float16* warr    = (_Float16*)A;                      // 2,400,000 B
    _Float16* yarr    = (_Float16*)(A + 2400000);          // 3,200,000 B
    int*      offsets = (int*)(A + 5600000);               // 1,048,580 B
    float2*   C       = (float2*)A;                        // 8 MB (aliases binning)
    unsigned* mmin    = (unsigned*)(A + 8400000);          // 32 B
    unsigned* mmax    = (unsigned*)(A + 8400064);          // 32 B

    double beta_d = M_PI * sqrt(19.45);   // BETA with alpha=2
    float beta = (float)beta_d;
    float inv_i0b = (float)(1.0 / i0_host(beta_d));
    float beta2 = (float)(beta_d * beta_d);

    hipMemsetAsync(counts, 0, NBINS * sizeof(int), stream);

    count_bins<<<(MPTS + 255) / 256, 256, 0, stream>>>((const float2*)uv, counts);

    scan1<<<256, 1024, 0, stream>>>(counts, offsets, bsum);
    scan2<<<1, 256, 0, stream>>>(bsum, boff, mmin, mmax);
    scan3<<<256, 1024, 0, stream>>>(offsets, boff);

    fill_records<<<(MPTS + 255) / 256, 256, 0, stream>>>(
        (const float2*)uv, y_real, y_imag, weights, offsets, counts,
        warr, yarr, beta, inv_i0b);

    gather_grid<<<NBINS / 256, 256, 0, stream>>>(offsets, warr, yarr, grid);

    fftA<<<512, 512, 0, stream>>>((const float2*)grid, C);

    fftB<<<512, 256, 0, stream>>>(C, img, beta2, mmin, mmax);

    norm_k<<<(BB * NN * NN) / 256, 256, 0, stream>>>(img, mmin, mmax, out);
}